// Round 4
// baseline (331.247 us; speedup 1.0000x reference)
//
#include <hip/hip_runtime.h>
#include <hip/hip_bf16.h>

typedef float f32x4 __attribute__((ext_vector_type(4)));
typedef float fvec4 __attribute__((ext_vector_type(4)));
typedef __bf16 bf16x8 __attribute__((ext_vector_type(8)));

__device__ inline float fexp2(float x) {
#if __has_builtin(__builtin_amdgcn_exp2f)
    return __builtin_amdgcn_exp2f(x);
#else
    return exp2f(x);
#endif
}

#define MFMA_BF16(a, b, c) __builtin_amdgcn_mfma_f32_16x16x32_bf16((a), (b), (c), 0, 0, 0)

__device__ __forceinline__ void gl2lds16(const void* g, void* l) {
    __builtin_amdgcn_global_load_lds((const __attribute__((address_space(1))) void*)g,
                                     (__attribute__((address_space(3))) void*)l, 16, 0, 0);
}

// seg offsets (elements) inside compact Q/K/V buffers: [seg0 12x2048][seg1 12x4096][seg2 12x2048] x64d
#define SEG1OFF ((size_t)12 * 2048 * 64)
#define SEG2OFF ((size_t)12 * 6144 * 64)
#define QSCALE 0.18033688f  // SCALE * log2(e)

// ---------------- W [K=768][N] f32 -> Wt [N][768] bf16 ----------------------------
__global__ __launch_bounds__(256) void transpose_cvt_kernel(const float* __restrict__ src,
                                                            __bf16* __restrict__ dst, int N) {
    int n = blockIdx.x * 256 + threadIdx.x;
    int kg = blockIdx.y;
    if (n >= N) return;
    bf16x8 o;
#pragma unroll
    for (int j = 0; j < 8; j++) o[j] = (__bf16)src[(size_t)(kg * 8 + j) * N + n];
    *(bf16x8*)&dst[(size_t)n * 768 + kg * 8] = o;
}

// ---- Vc compact [seg][head][pos][64] -> Vt [seg][head][64][Lc] in MFMA-k order ----
__global__ __launch_bounds__(256) void vtrans_kernel(const __bf16* __restrict__ Vc,
                                                     __bf16* __restrict__ Vt) {
    __shared__ __bf16 T[64][68];
    int bid = blockIdx.x;
    int Lc, head, t;
    size_t soff;
    if (bid < 768)       { Lc = 4096; head = bid >> 6; t = bid & 63; soff = SEG1OFF; }
    else if (bid < 1152) { int i = bid - 768; Lc = 2048; head = i >> 5; t = i & 31; soff = 0; }
    else                 { int i = bid - 1152; Lc = 2048; head = i >> 5; t = i & 31; soff = SEG2OFF; }
    const __bf16* src = Vc + soff + (size_t)head * Lc * 64;
    __bf16* dst = Vt + soff + (size_t)head * 64 * Lc;
    int tid = threadIdx.x;
#pragma unroll
    for (int it = 0; it < 2; it++) {
        int s = tid + it * 256;
        int kvr = s >> 3, d8 = (s & 7) * 8;
        bf16x8 vv = *(const bf16x8*)&src[(size_t)(t * 64 + kvr) * 64 + d8];
#pragma unroll
        for (int j = 0; j < 8; j++) T[d8 + j][kvr] = vv[j];
    }
    __syncthreads();
#pragma unroll
    for (int it = 0; it < 2; it++) {
        int s = tid + it * 256;
        int d = s >> 3, ck = s & 7;
        int kb = (ck >> 2) * 32 + (ck & 3) * 4;
        bf16x8 o;
#pragma unroll
        for (int J = 0; J < 8; J++) o[J] = T[d][kb + (J & 3) + (J >> 2) * 16];
        *(bf16x8*)&dst[(size_t)d * Lc + t * 64 + ck * 8] = o;
    }
}

// ---------------- bf16 MFMA GEMM ---------------------------------------------------
// mode 0: A=f32 x, writes compact Qc(scaled)/Kc/Vc via LDS-transposed coalesced stores.
// mode 1: A=bf16 attnF, writes f32 Co + bias (direct stores).
__global__ __launch_bounds__(256, 2) void gemm_kernel(
    const float* __restrict__ Af, const __bf16* __restrict__ Ab,
    const __bf16* __restrict__ Bt, const float* __restrict__ bias,
    __bf16* __restrict__ Qc, __bf16* __restrict__ Kc, __bf16* __restrict__ Vc,
    float* __restrict__ Co, int mode) {
    __shared__ __align__(16) char smem[36864];
    __bf16* Al = (__bf16*)smem;        // [128][72]
    __bf16* Bl = Al + 128 * 72;        // [128][72]
    __bf16* T  = (__bf16*)smem;        // [128][136] epilogue tile (reuse)
    int tid = threadIdx.x;
    int wave = tid >> 6, lane = tid & 63;
    int quad = lane >> 4, l15 = lane & 15;
    int bm = blockIdx.x * 128, bn = blockIdx.y * 128;
    int wm = (wave >> 1) * 64, wn = (wave & 1) * 64;
    int lr = tid >> 3, lc = (tid & 7) * 8;
    f32x4 acc[4][4] = {};
    for (int k0 = 0; k0 < 768; k0 += 64) {
        __syncthreads();
#pragma unroll
        for (int i = 0; i < 4; i++) {
            int r = i * 32 + lr;
            if (mode == 0) {
                const float* ap = &Af[(size_t)(bm + r) * 768 + k0 + lc];
                fvec4 a0 = *(const fvec4*)ap;
                fvec4 a1 = *(const fvec4*)(ap + 4);
                bf16x8 av;
                av[0] = (__bf16)a0[0]; av[1] = (__bf16)a0[1]; av[2] = (__bf16)a0[2]; av[3] = (__bf16)a0[3];
                av[4] = (__bf16)a1[0]; av[5] = (__bf16)a1[1]; av[6] = (__bf16)a1[2]; av[7] = (__bf16)a1[3];
                *(bf16x8*)&Al[r * 72 + lc] = av;
            } else {
                *(bf16x8*)&Al[r * 72 + lc] = *(const bf16x8*)&Ab[(size_t)(bm + r) * 768 + k0 + lc];
            }
            *(bf16x8*)&Bl[r * 72 + lc] = *(const bf16x8*)&Bt[(size_t)(bn + r) * 768 + k0 + lc];
        }
        __syncthreads();
#pragma unroll
        for (int ks = 0; ks < 2; ks++) {
            int ko = ks * 32 + quad * 8;
            bf16x8 af[4], bfr[4];
#pragma unroll
            for (int i = 0; i < 4; i++) af[i] = *(const bf16x8*)&Al[(wm + i * 16 + l15) * 72 + ko];
#pragma unroll
            for (int j = 0; j < 4; j++) bfr[j] = *(const bf16x8*)&Bl[(wn + j * 16 + l15) * 72 + ko];
#pragma unroll
            for (int i = 0; i < 4; i++)
#pragma unroll
                for (int j = 0; j < 4; j++)
                    acc[i][j] = MFMA_BF16(af[i], bfr[j], acc[i][j]);
        }
    }
    if (mode == 0) {
        int which = blockIdx.y / 6;             // uniform: 0=Q 1=K 2=V
        int h0 = (blockIdx.y % 6) * 2;          // first head of this 128-col block
        float scl = which == 0 ? QSCALE : 1.0f;
        float bv[4];
#pragma unroll
        for (int j = 0; j < 4; j++) bv[j] = bias[bn + wn + j * 16 + l15];
        __syncthreads();  // done reading Al/Bl
#pragma unroll
        for (int i = 0; i < 4; i++)
#pragma unroll
            for (int j = 0; j < 4; j++) {
                int col = wn + j * 16 + l15;
#pragma unroll
                for (int r = 0; r < 4; r++) {
                    int row = wm + i * 16 + quad * 4 + r;
                    int ch = ((col >> 3) & 8) | (((col >> 3) & 7) ^ (row & 7));
                    T[row * 136 + ch * 8 + (col & 7)] =
                        (__bf16)((acc[i][j][r] + bv[j]) * scl);
                }
            }
        __syncthreads();
        __bf16* dst = which == 0 ? Qc : (which == 1 ? Kc : Vc);
        int rr = tid >> 4;        // 0..15
        int c8 = tid & 15;        // 0..15
        int hh = c8 >> 3, d8 = c8 & 7;
        int h = h0 + hh;
        __bf16* p0 = dst + ((size_t)h * 2048 * 64) + d8 * 8;
        __bf16* p1 = dst + SEG1OFF + ((size_t)h * 4096 * 64) + d8 * 8;
        __bf16* p2 = dst + SEG2OFF + ((size_t)h * 2048 * 64) + d8 * 8;
#pragma unroll
        for (int pass = 0; pass < 8; pass++) {
            int row = pass * 16 + rr;
            int pos = bm + row;
            int ch = (c8 & 8) | ((c8 & 7) ^ (row & 7));
            bf16x8 v = *(const bf16x8*)&T[row * 136 + ch * 8];
            if (pos < 2048) *(bf16x8*)&p0[(size_t)pos * 64] = v;
            if (!(pos & 1)) *(bf16x8*)&p1[(size_t)(pos >> 1) * 64] = v;
            if (!(pos & 3)) *(bf16x8*)&p2[(size_t)(pos >> 2) * 64] = v;
        }
    } else {
#pragma unroll
        for (int j = 0; j < 4; j++) {
            int c = bn + wn + j * 16 + l15;
            float bv = bias[c];
#pragma unroll
            for (int i = 0; i < 4; i++)
#pragma unroll
                for (int r = 0; r < 4; r++) {
                    int row = bm + wm + i * 16 + quad * 4 + r;
                    Co[(size_t)row * 768 + c] = acc[i][j][r] + bv;
                }
        }
    }
}

// ---------------- fused flash attention: S^T form, no-max, kv-split, dbuf DMA ------
// 576 uniform blocks x 32 iters; 64 q per wave (256 q/block). Double-buffered K/V LDS:
// DMA for iter nt+1 issued right after the barrier that publishes iter nt's buffer,
// so the vmcnt(0) drain at the next barrier has a full compute iteration of slack.
__global__ __launch_bounds__(256, 2) void attn_kernel(
    const __bf16* __restrict__ Qcb, const __bf16* __restrict__ Kcb,
    const __bf16* __restrict__ Vtb,
    float* __restrict__ O0, float* __restrict__ O1a, float* __restrict__ O1b,
    float* __restrict__ O2, float* __restrict__ L0, float* __restrict__ L1a,
    float* __restrict__ L1b, float* __restrict__ L2) {
    __shared__ __bf16 Kl[2 * 4096];
    __shared__ __bf16 Vl[2 * 4096];
    int bid = blockIdx.x;
    int seg, half = 0, head, qt, Lc;
    if (bid < 384)      { head = bid >> 5; int r = bid & 31; qt = r >> 1; half = r & 1; Lc = 4096; seg = 1; }
    else if (bid < 480) { int i = bid - 384; head = i >> 3; qt = i & 7; Lc = 2048; seg = 0; }
    else                { int i = bid - 480; head = i >> 3; qt = i & 7; Lc = 2048; seg = 2; }
    size_t soff = seg == 0 ? 0 : (seg == 1 ? SEG1OFF : SEG2OFF);
    const __bf16* Qh = Qcb + soff + (size_t)head * Lc * 64;
    const __bf16* Kh = Kcb + soff + (size_t)head * Lc * 64;
    const __bf16* Vh = Vtb + soff + (size_t)head * 64 * Lc;
    float* Ob;
    float* Lb;
    if (seg == 0)      { Ob = O0; Lb = L0 + head * 2048; }
    else if (seg == 1) { Ob = half ? O1b : O1a; Lb = (half ? L1b : L1a) + head * 4096; }
    else               { Ob = O2; Lb = L2 + head * 2048; }
    int kvb = (seg == 1) ? half * 32 : 0;
    int tid = threadIdx.x, wave = tid >> 6, lane = tid & 63;
    int quad = lane >> 4, l15 = lane & 15;
    bf16x8 qf[4][2];
#pragma unroll
    for (int qg = 0; qg < 4; qg++) {
        size_t qpos = (size_t)(qt * 256 + wave * 64 + qg * 16 + l15);
        qf[qg][0] = *(const bf16x8*)&Qh[qpos * 64 + quad * 8];
        qf[qg][1] = *(const bf16x8*)&Qh[qpos * 64 + 32 + quad * 8];
    }
    f32x4 o[4][4] = {};
    float lrun[4] = {0.f, 0.f, 0.f, 0.f};
    int kv0 = tid >> 3, cl0 = tid & 7;
    int kdb0 = cl0 ^ (kv0 & 7);
    int kv1 = kv0 + 32, kdb1 = cl0 ^ (kv1 & 7);
    char* KlB = (char*)Kl;
    char* VlB = (char*)Vl;
    int swz = l15 & 7;
    {   // prologue: buffer 0 <- tile 0
        int t0 = kvb * 64;
        gl2lds16(&Kh[(size_t)(t0 + kv0) * 64 + kdb0 * 8], KlB + wave * 1024);
        gl2lds16(&Kh[(size_t)(t0 + kv1) * 64 + kdb1 * 8], KlB + 4096 + wave * 1024);
        gl2lds16(&Vh[(size_t)kv0 * Lc + t0 + kdb0 * 8], VlB + wave * 1024);
        gl2lds16(&Vh[(size_t)kv1 * Lc + t0 + kdb1 * 8], VlB + 4096 + wave * 1024);
    }
    for (int nt = 0; nt < 32; nt++) {
        __syncthreads();  // drains DMA for buf[nt&1]; publishes it to all waves
        int cur = nt & 1;
        if (nt < 31) {
            int nb = (nt + 1) & 1;
            int t1 = (kvb + nt + 1) * 64;
            gl2lds16(&Kh[(size_t)(t1 + kv0) * 64 + kdb0 * 8], KlB + nb * 8192 + wave * 1024);
            gl2lds16(&Kh[(size_t)(t1 + kv1) * 64 + kdb1 * 8], KlB + nb * 8192 + 4096 + wave * 1024);
            gl2lds16(&Vh[(size_t)kv0 * Lc + t1 + kdb0 * 8], VlB + nb * 8192 + wave * 1024);
            gl2lds16(&Vh[(size_t)kv1 * Lc + t1 + kdb1 * 8], VlB + nb * 8192 + 4096 + wave * 1024);
        }
        const __bf16* Kt = Kl + cur * 4096;
        const __bf16* Vt_ = Vl + cur * 4096;
        bf16x8 kf[4][2];
#pragma unroll
        for (int c = 0; c < 4; c++) {
            int krow = (c * 16 + l15) * 64;
            kf[c][0] = *(const bf16x8*)&Kt[krow + ((quad ^ swz) * 8)];
            kf[c][1] = *(const bf16x8*)&Kt[krow + (((4 + quad) ^ swz) * 8)];
        }
        bf16x8 pf8[4][2];
#pragma unroll
        for (int qg = 0; qg < 4; qg++) {
            f32x4 sarr[4];
#pragma unroll
            for (int c = 0; c < 4; c++) {
                f32x4 z = {};
                z = MFMA_BF16(kf[c][0], qf[qg][0], z);
                sarr[c] = MFMA_BF16(kf[c][1], qf[qg][1], z);
            }
#pragma unroll
            for (int c = 0; c < 4; c++)
#pragma unroll
                for (int r = 0; r < 4; r++) {
                    float p = fexp2(sarr[c][r]);
                    lrun[qg] += p;
                    pf8[qg][c >> 1][(c & 1) * 4 + r] = (__bf16)p;
                }
        }
#pragma unroll
        for (int u = 0; u < 2; u++)
#pragma unroll
            for (int ds = 0; ds < 4; ds++) {
                bf16x8 vf = *(const bf16x8*)&Vt_[(ds * 16 + l15) * 64 + (((u * 4 + quad) ^ swz) * 8)];
#pragma unroll
                for (int qg = 0; qg < 4; qg++)
                    o[qg][ds] = MFMA_BF16(vf, pf8[qg][u], o[qg][ds]);
            }
    }
#pragma unroll
    for (int qg = 0; qg < 4; qg++) {
        float l = lrun[qg];
        l += __shfl_xor(l, 16, 64);
        l += __shfl_xor(l, 32, 64);
        int pos = qt * 256 + wave * 64 + qg * 16 + l15;
        float* orow = Ob + (size_t)pos * 768 + head * 64;
#pragma unroll
        for (int ds = 0; ds < 4; ds++)
            *(f32x4*)&orow[ds * 16 + quad * 4] = o[qg][ds];
        if (lane < 16) Lb[qt * 256 + wave * 64 + qg * 16 + lane] = l;
    }
}

// ---------------- combine: attnF[q][768] = (1/3) * sum_seg O_seg/l_seg, bf16 -------
__global__ __launch_bounds__(256) void combine_kernel(
    const float* __restrict__ O0, const float* __restrict__ O1a,
    const float* __restrict__ O1b, const float* __restrict__ O2,
    const float* __restrict__ L0, const float* __restrict__ L1a,
    const float* __restrict__ L1b, const float* __restrict__ L2,
    __bf16* __restrict__ attnF) {
    int g = blockIdx.x * 256 + threadIdx.x;  // 8192*96
    int q = g / 96;
    int cs = (g - q * 96) * 8;
    int head = cs >> 6;
    f32x4 a0 = {}, a1 = {};
    if (q < 2048) {
        float inv = 1.0f / L0[head * 2048 + q];
        const f32x4* p = (const f32x4*)&O0[(size_t)q * 768 + cs];
        a0 += p[0] * inv; a1 += p[1] * inv;
    }
    if (!(q & 1)) {
        int p1 = q >> 1;
        float inv = 1.0f / (L1a[head * 4096 + p1] + L1b[head * 4096 + p1]);
        const f32x4* pa = (const f32x4*)&O1a[(size_t)p1 * 768 + cs];
        const f32x4* pb = (const f32x4*)&O1b[(size_t)p1 * 768 + cs];
        a0 += (pa[0] + pb[0]) * inv; a1 += (pa[1] + pb[1]) * inv;
    }
    if (!(q & 3)) {
        int p2 = q >> 2;
        float inv = 1.0f / L2[head * 2048 + p2];
        const f32x4* p = (const f32x4*)&O2[(size_t)p2 * 768 + cs];
        a0 += p[0] * inv; a1 += p[1] * inv;
    }
    const float third = 1.0f / 3.0f;
    bf16x8 ov;
    ov[0] = (__bf16)(a0[0] * third); ov[1] = (__bf16)(a0[1] * third);
    ov[2] = (__bf16)(a0[2] * third); ov[3] = (__bf16)(a0[3] * third);
    ov[4] = (__bf16)(a1[0] * third); ov[5] = (__bf16)(a1[1] * third);
    ov[6] = (__bf16)(a1[2] * third); ov[7] = (__bf16)(a1[3] * third);
    *(bf16x8*)&attnF[(size_t)q * 768 + cs] = ov;
}

extern "C" void kernel_launch(void* const* d_in, const int* in_sizes, int n_in,
                              void* d_out, int out_size, void* d_ws, size_t ws_size,
                              hipStream_t stream) {
    const float* x    = (const float*)d_in[0];
    const float* Wqkv = (const float*)d_in[1];
    const float* bqkv = (const float*)d_in[2];
    const float* Wout = (const float*)d_in[3];
    const float* bout = (const float*)d_in[4];
    float* out = (float*)d_out;
    (void)in_sizes; (void)n_in; (void)out_size; (void)ws_size;

    char* ws = (char*)d_ws;
    size_t off = 0;
    auto take = [&](size_t bytes) -> void* {
        void* p = ws + off;
        off += (bytes + 255) & ~(size_t)255;
        return p;
    };
    const size_t QKV_ELEMS = (size_t)12 * 8192 * 64;  // compact seg-major total
    __bf16* WqkvT = (__bf16*)take((size_t)2304 * 768 * 2);
    __bf16* WoutT = (__bf16*)take((size_t)768 * 768 * 2);
    __bf16* Qc    = (__bf16*)take(QKV_ELEMS * 2);
    __bf16* Kc    = (__bf16*)take(QKV_ELEMS * 2);
    __bf16* Vc    = (__bf16*)take(QKV_ELEMS * 2);
    __bf16* Vt    = (__bf16*)take(QKV_ELEMS * 2);
    float*  O0    = (float*)take((size_t)2048 * 768 * 4);
    float*  O1a   = (float*)take((size_t)4096 * 768 * 4);
    float*  O1b   = (float*)take((size_t)4096 * 768 * 4);
    float*  O2    = (float*)take((size_t)2048 * 768 * 4);
    float*  L0    = (float*)take((size_t)12 * 2048 * 4);
    float*  L1a   = (float*)take((size_t)12 * 4096 * 4);
    float*  L1b   = (float*)take((size_t)12 * 4096 * 4);
    float*  L2    = (float*)take((size_t)12 * 2048 * 4);
    __bf16* attnF = Qc;  // alias: Qc dead after attn_kernel

    transpose_cvt_kernel<<<dim3(9, 96), 256, 0, stream>>>(Wqkv, WqkvT, 2304);
    transpose_cvt_kernel<<<dim3(3, 96), 256, 0, stream>>>(Wout, WoutT, 768);
    gemm_kernel<<<dim3(64, 18), 256, 0, stream>>>(x, nullptr, WqkvT, bqkv, Qc, Kc, Vc,
                                                  nullptr, 0);
    vtrans_kernel<<<1536, 256, 0, stream>>>(Vc, Vt);
    attn_kernel<<<576, 256, 0, stream>>>(Qc, Kc, Vt, O0, O1a, O1b, O2, L0, L1a, L1b, L2);
    combine_kernel<<<3072, 256, 0, stream>>>(O0, O1a, O1b, O2, L0, L1a, L1b, L2, attnF);
    gemm_kernel<<<dim3(64, 6), 256, 0, stream>>>(nullptr, attnF, WoutT, bout, nullptr,
                                                 nullptr, nullptr, out, 1);
}

// Round 5
// 316.429 us; speedup vs baseline: 1.0468x; 1.0468x over previous
//
#include <hip/hip_runtime.h>
#include <hip/hip_bf16.h>

typedef float f32x4 __attribute__((ext_vector_type(4)));
typedef float fvec4 __attribute__((ext_vector_type(4)));
typedef __bf16 bf16x8 __attribute__((ext_vector_type(8)));

__device__ inline float fexp2(float x) {
#if __has_builtin(__builtin_amdgcn_exp2f)
    return __builtin_amdgcn_exp2f(x);
#else
    return exp2f(x);
#endif
}

#define MFMA_BF16(a, b, c) __builtin_amdgcn_mfma_f32_16x16x32_bf16((a), (b), (c), 0, 0, 0)

__device__ __forceinline__ void gl2lds16(const void* g, void* l) {
    __builtin_amdgcn_global_load_lds((const __attribute__((address_space(1))) void*)g,
                                     (__attribute__((address_space(3))) void*)l, 16, 0, 0);
}

// seg offsets (elements) inside compact Q/K/V buffers: [seg0 12x2048][seg1 12x4096][seg2 12x2048] x64d
#define SEG1OFF ((size_t)12 * 2048 * 64)
#define SEG2OFF ((size_t)12 * 6144 * 64)
#define QSCALE 0.18033688f  // SCALE * log2(e)

// ---------------- f32 -> bf16 elementwise convert (8 elems/thread) ----------------
__global__ __launch_bounds__(256) void cvt_kernel(const float* __restrict__ in,
                                                  __bf16* __restrict__ out, int n8) {
    int i = blockIdx.x * 256 + threadIdx.x;
    if (i >= n8) return;
    fvec4 a = ((const fvec4*)in)[2 * i];
    fvec4 b = ((const fvec4*)in)[2 * i + 1];
    bf16x8 o;
    o[0] = (__bf16)a[0]; o[1] = (__bf16)a[1]; o[2] = (__bf16)a[2]; o[3] = (__bf16)a[3];
    o[4] = (__bf16)b[0]; o[5] = (__bf16)b[1]; o[6] = (__bf16)b[2]; o[7] = (__bf16)b[3];
    ((bf16x8*)out)[i] = o;
}

// ---------------- W [K=768][N] f32 -> Wt [N][768] bf16 ----------------------------
__global__ __launch_bounds__(256) void transpose_cvt_kernel(const float* __restrict__ src,
                                                            __bf16* __restrict__ dst, int N) {
    int n = blockIdx.x * 256 + threadIdx.x;
    int kg = blockIdx.y;
    if (n >= N) return;
    bf16x8 o;
#pragma unroll
    for (int j = 0; j < 8; j++) o[j] = (__bf16)src[(size_t)(kg * 8 + j) * N + n];
    *(bf16x8*)&dst[(size_t)n * 768 + kg * 8] = o;
}

// ---- Vc compact [seg][head][pos][64] -> Vt [seg][head][64][Lc] in MFMA-k order ----
__global__ __launch_bounds__(256) void vtrans_kernel(const __bf16* __restrict__ Vc,
                                                     __bf16* __restrict__ Vt) {
    __shared__ __bf16 T[64][68];
    int bid = blockIdx.x;
    int Lc, head, t;
    size_t soff;
    if (bid < 768)       { Lc = 4096; head = bid >> 6; t = bid & 63; soff = SEG1OFF; }
    else if (bid < 1152) { int i = bid - 768; Lc = 2048; head = i >> 5; t = i & 31; soff = 0; }
    else                 { int i = bid - 1152; Lc = 2048; head = i >> 5; t = i & 31; soff = SEG2OFF; }
    const __bf16* src = Vc + soff + (size_t)head * Lc * 64;
    __bf16* dst = Vt + soff + (size_t)head * 64 * Lc;
    int tid = threadIdx.x;
#pragma unroll
    for (int it = 0; it < 2; it++) {
        int s = tid + it * 256;
        int kvr = s >> 3, d8 = (s & 7) * 8;
        bf16x8 vv = *(const bf16x8*)&src[(size_t)(t * 64 + kvr) * 64 + d8];
#pragma unroll
        for (int j = 0; j < 8; j++) T[d8 + j][kvr] = vv[j];
    }
    __syncthreads();
#pragma unroll
    for (int it = 0; it < 2; it++) {
        int s = tid + it * 256;
        int d = s >> 3, ck = s & 7;
        int kb = (ck >> 2) * 32 + (ck & 3) * 4;
        bf16x8 o;
#pragma unroll
        for (int J = 0; J < 8; J++) o[J] = T[d][kb + (J & 3) + (J >> 2) * 16];
        *(bf16x8*)&dst[(size_t)d * Lc + t * 64 + ck * 8] = o;
    }
}

// ---------------- bf16 MFMA GEMM, DMA-staged ---------------------------------------
// A bf16 [M][768], Bt bf16 [N][768]. Staging via global_load_lds into unpadded
// XOR-chunk-swizzled [128][64] tiles (2-way only = free). m97 2-barrier K-loop.
// mode 0: writes compact Qc(scaled)/Kc/Vc via LDS-transposed coalesced stores.
// mode 1: writes f32 Co + bias directly.
__global__ __launch_bounds__(256, 2) void gemm_kernel(
    const __bf16* __restrict__ Ab, const __bf16* __restrict__ Bt,
    const float* __restrict__ bias,
    __bf16* __restrict__ Qc, __bf16* __restrict__ Kc, __bf16* __restrict__ Vc,
    float* __restrict__ Co, int mode) {
    __shared__ __align__(16) char smem[34816];  // staging 32 KB; T tile 34 KB (reuse)
    __bf16* Al = (__bf16*)smem;                 // [128][64] swizzled
    __bf16* Bl = Al + 128 * 64;
    __bf16* T  = (__bf16*)smem;                 // [128][136] epilogue tile
    int tid = threadIdx.x;
    int wave = tid >> 6, lane = tid & 63;
    int quad = lane >> 4, l15 = lane & 15;
    int bm = blockIdx.x * 128, bn = blockIdx.y * 128;
    int wm = (wave >> 1) * 64, wn = (wave & 1) * 64;
    // DMA slot decode: slot s (0..1023 per operand) -> row s>>3, chunk (s&7)^(row&7)
    int swzA = tid & 7;        // lane's chunk-pos within its row group
    f32x4 acc[4][4] = {};
    for (int k0 = 0; k0 < 768; k0 += 64) {
        __syncthreads();
#pragma unroll
        for (int j = 0; j < 4; j++) {
            int s = j * 256 + tid;
            int row = s >> 3;
            int ch = swzA ^ (row & 7);
            gl2lds16(&Ab[(size_t)(bm + row) * 768 + k0 + ch * 8],
                     (char*)smem + j * 4096 + wave * 1024);
            gl2lds16(&Bt[(size_t)(bn + row) * 768 + k0 + ch * 8],
                     (char*)smem + 16384 + j * 4096 + wave * 1024);
        }
        __syncthreads();
#pragma unroll
        for (int ks = 0; ks < 2; ks++) {
            bf16x8 af[4], bfr[4];
#pragma unroll
            for (int i = 0; i < 4; i++) {
                int row = wm + i * 16 + l15;
                af[i] = *(const bf16x8*)&Al[row * 64 + (((ks * 4 + quad) ^ (row & 7)) * 8)];
            }
#pragma unroll
            for (int j = 0; j < 4; j++) {
                int row = wn + j * 16 + l15;
                bfr[j] = *(const bf16x8*)&Bl[row * 64 + (((ks * 4 + quad) ^ (row & 7)) * 8)];
            }
#pragma unroll
            for (int i = 0; i < 4; i++)
#pragma unroll
                for (int j = 0; j < 4; j++)
                    acc[i][j] = MFMA_BF16(af[i], bfr[j], acc[i][j]);
        }
    }
    if (mode == 0) {
        int which = blockIdx.y / 6;             // uniform: 0=Q 1=K 2=V
        int h0 = (blockIdx.y % 6) * 2;          // first head of this 128-col block
        float scl = which == 0 ? QSCALE : 1.0f;
        float bv[4];
#pragma unroll
        for (int j = 0; j < 4; j++) bv[j] = bias[bn + wn + j * 16 + l15];
        __syncthreads();  // done reading Al/Bl
#pragma unroll
        for (int i = 0; i < 4; i++)
#pragma unroll
            for (int j = 0; j < 4; j++) {
                int col = wn + j * 16 + l15;
#pragma unroll
                for (int r = 0; r < 4; r++) {
                    int row = wm + i * 16 + quad * 4 + r;
                    int ch = ((col >> 3) & 8) | (((col >> 3) & 7) ^ (row & 7));
                    T[row * 136 + ch * 8 + (col & 7)] =
                        (__bf16)((acc[i][j][r] + bv[j]) * scl);
                }
            }
        __syncthreads();
        __bf16* dst = which == 0 ? Qc : (which == 1 ? Kc : Vc);
        int rr = tid >> 4;        // 0..15
        int c8 = tid & 15;        // 0..15
        int hh = c8 >> 3, d8 = c8 & 7;
        int h = h0 + hh;
        __bf16* p0 = dst + ((size_t)h * 2048 * 64) + d8 * 8;
        __bf16* p1 = dst + SEG1OFF + ((size_t)h * 4096 * 64) + d8 * 8;
        __bf16* p2 = dst + SEG2OFF + ((size_t)h * 2048 * 64) + d8 * 8;
#pragma unroll
        for (int pass = 0; pass < 8; pass++) {
            int row = pass * 16 + rr;
            int pos = bm + row;
            int ch = (c8 & 8) | ((c8 & 7) ^ (row & 7));
            bf16x8 v = *(const bf16x8*)&T[row * 136 + ch * 8];
            if (pos < 2048) *(bf16x8*)&p0[(size_t)pos * 64] = v;
            if (!(pos & 1)) *(bf16x8*)&p1[(size_t)(pos >> 1) * 64] = v;
            if (!(pos & 3)) *(bf16x8*)&p2[(size_t)(pos >> 2) * 64] = v;
        }
    } else {
        int quad4 = quad * 4;
#pragma unroll
        for (int j = 0; j < 4; j++) {
            int c = bn + wn + j * 16 + l15;
            float bv = bias[c];
#pragma unroll
            for (int i = 0; i < 4; i++)
#pragma unroll
                for (int r = 0; r < 4; r++) {
                    int row = bm + wm + i * 16 + quad4 + r;
                    Co[(size_t)row * 768 + c] = acc[i][j][r] + bv;
                }
        }
    }
}

// ---------------- fused flash attention: S^T, no-max, kv-split, dbuf DMA -----------
// 1152 uniform blocks x 32 iters; 2 waves/block, 64 q/wave (128 q/block).
// Double-buffered K/V LDS: prefetch nt+1 issued right after the barrier publishing
// nt, so the vmcnt(0) drain at the next barrier has a full compute phase of slack.
__global__ __launch_bounds__(128, 4) void attn_kernel(
    const __bf16* __restrict__ Qcb, const __bf16* __restrict__ Kcb,
    const __bf16* __restrict__ Vtb,
    float* __restrict__ O0, float* __restrict__ O1a, float* __restrict__ O1b,
    float* __restrict__ O2, float* __restrict__ L0, float* __restrict__ L1a,
    float* __restrict__ L1b, float* __restrict__ L2) {
    __shared__ __bf16 Kl[2 * 4096];
    __shared__ __bf16 Vl[2 * 4096];
    int bid = blockIdx.x;
    int seg, half = 0, head, qt, Lc;
    if (bid < 768)      { head = bid >> 6; int r = bid & 63; qt = r >> 1; half = r & 1; Lc = 4096; seg = 1; }
    else if (bid < 960) { int i = bid - 768; head = i >> 4; qt = i & 15; Lc = 2048; seg = 0; }
    else                { int i = bid - 960; head = i >> 4; qt = i & 15; Lc = 2048; seg = 2; }
    size_t soff = seg == 0 ? 0 : (seg == 1 ? SEG1OFF : SEG2OFF);
    const __bf16* Qh = Qcb + soff + (size_t)head * Lc * 64;
    const __bf16* Kh = Kcb + soff + (size_t)head * Lc * 64;
    const __bf16* Vh = Vtb + soff + (size_t)head * 64 * Lc;
    float* Ob;
    float* Lb;
    if (seg == 0)      { Ob = O0; Lb = L0 + head * 2048; }
    else if (seg == 1) { Ob = half ? O1b : O1a; Lb = (half ? L1b : L1a) + head * 4096; }
    else               { Ob = O2; Lb = L2 + head * 2048; }
    int kvb = (seg == 1) ? half * 32 : 0;
    int tid = threadIdx.x, wave = tid >> 6, lane = tid & 63;
    int quad = lane >> 4, l15 = lane & 15;
    bf16x8 qf[4][2];
#pragma unroll
    for (int qg = 0; qg < 4; qg++) {
        size_t qpos = (size_t)(qt * 128 + wave * 64 + qg * 16 + l15);
        qf[qg][0] = *(const bf16x8*)&Qh[qpos * 64 + quad * 8];
        qf[qg][1] = *(const bf16x8*)&Qh[qpos * 64 + 32 + quad * 8];
    }
    f32x4 o[4][4] = {};
    float lrun[4] = {0.f, 0.f, 0.f, 0.f};
    char* KlB = (char*)Kl;
    char* VlB = (char*)Vl;
    int swz = l15 & 7;
    // DMA slot decode: 8 calls/iter, slot s = j*128 + tid, row s>>3, chunk (s&7)^(row&7)
    int rows_[4], chs_[4];
#pragma unroll
    for (int j = 0; j < 4; j++) {
        int s = j * 128 + tid;
        rows_[j] = s >> 3;
        chs_[j] = (s & 7) ^ (rows_[j] & 7);
    }
    {   // prologue: buffer 0 <- tile kvb
        int t0 = kvb * 64;
#pragma unroll
        for (int j = 0; j < 4; j++) {
            gl2lds16(&Kh[(size_t)(t0 + rows_[j]) * 64 + chs_[j] * 8],
                     KlB + j * 2048 + wave * 1024);
            gl2lds16(&Vh[(size_t)rows_[j] * Lc + t0 + chs_[j] * 8],
                     VlB + j * 2048 + wave * 1024);
        }
    }
    for (int nt = 0; nt < 32; nt++) {
        __syncthreads();  // drains DMA for buf[nt&1]; publishes it to both waves
        int cur = nt & 1;
        if (nt < 31) {
            int nb = 8192 * ((nt + 1) & 1);
            int t1 = (kvb + nt + 1) * 64;
#pragma unroll
            for (int j = 0; j < 4; j++) {
                gl2lds16(&Kh[(size_t)(t1 + rows_[j]) * 64 + chs_[j] * 8],
                         KlB + nb + j * 2048 + wave * 1024);
                gl2lds16(&Vh[(size_t)rows_[j] * Lc + t1 + chs_[j] * 8],
                         VlB + nb + j * 2048 + wave * 1024);
            }
        }
        const __bf16* Kt = Kl + cur * 4096;
        const __bf16* Vt_ = Vl + cur * 4096;
        bf16x8 kf[4][2];
#pragma unroll
        for (int c = 0; c < 4; c++) {
            int krow = (c * 16 + l15) * 64;
            kf[c][0] = *(const bf16x8*)&Kt[krow + ((quad ^ swz) * 8)];
            kf[c][1] = *(const bf16x8*)&Kt[krow + (((4 + quad) ^ swz) * 8)];
        }
        bf16x8 pf8[4][2];
#pragma unroll
        for (int qg = 0; qg < 4; qg++) {
            f32x4 sarr[4];
#pragma unroll
            for (int c = 0; c < 4; c++) {
                f32x4 z = {};
                z = MFMA_BF16(kf[c][0], qf[qg][0], z);
                sarr[c] = MFMA_BF16(kf[c][1], qf[qg][1], z);
            }
#pragma unroll
            for (int c = 0; c < 4; c++)
#pragma unroll
                for (int r = 0; r < 4; r++) {
                    float p = fexp2(sarr[c][r]);
                    lrun[qg] += p;
                    pf8[qg][c >> 1][(c & 1) * 4 + r] = (__bf16)p;
                }
        }
#pragma unroll
        for (int u = 0; u < 2; u++)
#pragma unroll
            for (int ds = 0; ds < 4; ds++) {
                bf16x8 vf = *(const bf16x8*)&Vt_[(ds * 16 + l15) * 64 + (((u * 4 + quad) ^ swz) * 8)];
#pragma unroll
                for (int qg = 0; qg < 4; qg++)
                    o[qg][ds] = MFMA_BF16(vf, pf8[qg][u], o[qg][ds]);
            }
    }
#pragma unroll
    for (int qg = 0; qg < 4; qg++) {
        float l = lrun[qg];
        l += __shfl_xor(l, 16, 64);
        l += __shfl_xor(l, 32, 64);
        int pos = qt * 128 + wave * 64 + qg * 16 + l15;
        float* orow = Ob + (size_t)pos * 768 + head * 64;
#pragma unroll
        for (int ds = 0; ds < 4; ds++)
            *(f32x4*)&orow[ds * 16 + quad * 4] = o[qg][ds];
        if (lane < 16) Lb[qt * 128 + wave * 64 + qg * 16 + lane] = l;
    }
}

// ---------------- combine: attnF[q][768] = (1/3) * sum_seg O_seg/l_seg, bf16 -------
__global__ __launch_bounds__(256) void combine_kernel(
    const float* __restrict__ O0, const float* __restrict__ O1a,
    const float* __restrict__ O1b, const float* __restrict__ O2,
    const float* __restrict__ L0, const float* __restrict__ L1a,
    const float* __restrict__ L1b, const float* __restrict__ L2,
    __bf16* __restrict__ attnF) {
    int g = blockIdx.x * 256 + threadIdx.x;  // 8192*96
    int q = g / 96;
    int cs = (g - q * 96) * 8;
    int head = cs >> 6;
    f32x4 a0 = {}, a1 = {};
    if (q < 2048) {
        float inv = 1.0f / L0[head * 2048 + q];
        const f32x4* p = (const f32x4*)&O0[(size_t)q * 768 + cs];
        a0 += p[0] * inv; a1 += p[1] * inv;
    }
    if (!(q & 1)) {
        int p1 = q >> 1;
        float inv = 1.0f / (L1a[head * 4096 + p1] + L1b[head * 4096 + p1]);
        const f32x4* pa = (const f32x4*)&O1a[(size_t)p1 * 768 + cs];
        const f32x4* pb = (const f32x4*)&O1b[(size_t)p1 * 768 + cs];
        a0 += (pa[0] + pb[0]) * inv; a1 += (pa[1] + pb[1]) * inv;
    }
    if (!(q & 3)) {
        int p2 = q >> 2;
        float inv = 1.0f / L2[head * 2048 + p2];
        const f32x4* p = (const f32x4*)&O2[(size_t)p2 * 768 + cs];
        a0 += p[0] * inv; a1 += p[1] * inv;
    }
    const float third = 1.0f / 3.0f;
    bf16x8 ov;
    ov[0] = (__bf16)(a0[0] * third); ov[1] = (__bf16)(a0[1] * third);
    ov[2] = (__bf16)(a0[2] * third); ov[3] = (__bf16)(a0[3] * third);
    ov[4] = (__bf16)(a1[0] * third); ov[5] = (__bf16)(a1[1] * third);
    ov[6] = (__bf16)(a1[2] * third); ov[7] = (__bf16)(a1[3] * third);
    *(bf16x8*)&attnF[(size_t)q * 768 + cs] = ov;
}

extern "C" void kernel_launch(void* const* d_in, const int* in_sizes, int n_in,
                              void* d_out, int out_size, void* d_ws, size_t ws_size,
                              hipStream_t stream) {
    const float* x    = (const float*)d_in[0];
    const float* Wqkv = (const float*)d_in[1];
    const float* bqkv = (const float*)d_in[2];
    const float* Wout = (const float*)d_in[3];
    const float* bout = (const float*)d_in[4];
    float* out = (float*)d_out;
    (void)in_sizes; (void)n_in; (void)out_size; (void)ws_size;

    char* ws = (char*)d_ws;
    size_t off = 0;
    auto take = [&](size_t bytes) -> void* {
        void* p = ws + off;
        off += (bytes + 255) & ~(size_t)255;
        return p;
    };
    const size_t QKV_ELEMS = (size_t)12 * 8192 * 64;  // compact seg-major total
    __bf16* xb    = (__bf16*)take((size_t)8192 * 768 * 2);
    __bf16* WqkvT = (__bf16*)take((size_t)2304 * 768 * 2);
    __bf16* WoutT = (__bf16*)take((size_t)768 * 768 * 2);
    __bf16* Qc    = (__bf16*)take(QKV_ELEMS * 2);
    __bf16* Kc    = (__bf16*)take(QKV_ELEMS * 2);
    __bf16* Vc    = (__bf16*)take(QKV_ELEMS * 2);
    __bf16* Vt    = (__bf16*)take(QKV_ELEMS * 2);
    float*  O0    = (float*)take((size_t)2048 * 768 * 4);
    float*  O1a   = (float*)take((size_t)4096 * 768 * 4);
    float*  O1b   = (float*)take((size_t)4096 * 768 * 4);
    float*  O2    = (float*)take((size_t)2048 * 768 * 4);
    float*  L0    = (float*)take((size_t)12 * 2048 * 4);
    float*  L1a   = (float*)take((size_t)12 * 4096 * 4);
    float*  L1b   = (float*)take((size_t)12 * 4096 * 4);
    float*  L2    = (float*)take((size_t)12 * 2048 * 4);
    __bf16* attnF = Qc;  // alias: Qc dead after attn_kernel

    cvt_kernel<<<3072, 256, 0, stream>>>(x, xb, 8192 * 768 / 8);
    transpose_cvt_kernel<<<dim3(9, 96), 256, 0, stream>>>(Wqkv, WqkvT, 2304);
    transpose_cvt_kernel<<<dim3(3, 96), 256, 0, stream>>>(Wout, WoutT, 768);
    gemm_kernel<<<dim3(64, 18), 256, 0, stream>>>(xb, WqkvT, bqkv, Qc, Kc, Vc,
                                                  nullptr, 0);
    vtrans_kernel<<<1536, 256, 0, stream>>>(Vc, Vt);
    attn_kernel<<<1152, 128, 0, stream>>>(Qc, Kc, Vt, O0, O1a, O1b, O2, L0, L1a, L1b, L2);
    combine_kernel<<<3072, 256, 0, stream>>>(O0, O1a, O1b, O2, L0, L1a, L1b, L2, attnF);
    gemm_kernel<<<dim3(64, 6), 256, 0, stream>>>(attnF, WoutT, bout, nullptr, nullptr,
                                                 nullptr, out, 1);
}

// Round 6
// 259.668 us; speedup vs baseline: 1.2757x; 1.2186x over previous
//
#include <hip/hip_runtime.h>
#include <hip/hip_bf16.h>

typedef float f32x4 __attribute__((ext_vector_type(4)));
typedef float fvec4 __attribute__((ext_vector_type(4)));
typedef __bf16 bf16x8 __attribute__((ext_vector_type(8)));

__device__ inline float fexp2(float x) {
#if __has_builtin(__builtin_amdgcn_exp2f)
    return __builtin_amdgcn_exp2f(x);
#else
    return exp2f(x);
#endif
}

#define MFMA_BF16(a, b, c) __builtin_amdgcn_mfma_f32_16x16x32_bf16((a), (b), (c), 0, 0, 0)

__device__ __forceinline__ void gl2lds16(const void* g, void* l) {
    __builtin_amdgcn_global_load_lds((const __attribute__((address_space(1))) void*)g,
                                     (__attribute__((address_space(3))) void*)l, 16, 0, 0);
}

// seg offsets (elements) inside compact Q/K/V buffers: [seg0 12x2048][seg1 12x4096][seg2 12x2048] x64d
#define SEG1OFF ((size_t)12 * 2048 * 64)
#define SEG2OFF ((size_t)12 * 6144 * 64)
#define QSCALE 0.18033688f  // SCALE * log2(e)

// ---------------- f32 -> bf16 elementwise convert (8 elems/thread) ----------------
__global__ __launch_bounds__(256) void cvt_kernel(const float* __restrict__ in,
                                                  __bf16* __restrict__ out, int n8) {
    int i = blockIdx.x * 256 + threadIdx.x;
    if (i >= n8) return;
    fvec4 a = ((const fvec4*)in)[2 * i];
    fvec4 b = ((const fvec4*)in)[2 * i + 1];
    bf16x8 o;
    o[0] = (__bf16)a[0]; o[1] = (__bf16)a[1]; o[2] = (__bf16)a[2]; o[3] = (__bf16)a[3];
    o[4] = (__bf16)b[0]; o[5] = (__bf16)b[1]; o[6] = (__bf16)b[2]; o[7] = (__bf16)b[3];
    ((bf16x8*)out)[i] = o;
}

// ---------------- W [K=768][N] f32 -> Wt [N][768] bf16 ----------------------------
__global__ __launch_bounds__(256) void transpose_cvt_kernel(const float* __restrict__ src,
                                                            __bf16* __restrict__ dst, int N) {
    int n = blockIdx.x * 256 + threadIdx.x;
    int kg = blockIdx.y;
    if (n >= N) return;
    bf16x8 o;
#pragma unroll
    for (int j = 0; j < 8; j++) o[j] = (__bf16)src[(size_t)(kg * 8 + j) * N + n];
    *(bf16x8*)&dst[(size_t)n * 768 + kg * 8] = o;
}

// ---- Vc compact [seg][head][pos][64] -> Vt [seg][head][64][Lc] in MFMA-k order ----
__global__ __launch_bounds__(256) void vtrans_kernel(const __bf16* __restrict__ Vc,
                                                     __bf16* __restrict__ Vt) {
    __shared__ __bf16 T[64][68];
    int bid = blockIdx.x;
    int Lc, head, t;
    size_t soff;
    if (bid < 768)       { Lc = 4096; head = bid >> 6; t = bid & 63; soff = SEG1OFF; }
    else if (bid < 1152) { int i = bid - 768; Lc = 2048; head = i >> 5; t = i & 31; soff = 0; }
    else                 { int i = bid - 1152; Lc = 2048; head = i >> 5; t = i & 31; soff = SEG2OFF; }
    const __bf16* src = Vc + soff + (size_t)head * Lc * 64;
    __bf16* dst = Vt + soff + (size_t)head * 64 * Lc;
    int tid = threadIdx.x;
#pragma unroll
    for (int it = 0; it < 2; it++) {
        int s = tid + it * 256;
        int kvr = s >> 3, d8 = (s & 7) * 8;
        bf16x8 vv = *(const bf16x8*)&src[(size_t)(t * 64 + kvr) * 64 + d8];
#pragma unroll
        for (int j = 0; j < 8; j++) T[d8 + j][kvr] = vv[j];
    }
    __syncthreads();
#pragma unroll
    for (int it = 0; it < 2; it++) {
        int s = tid + it * 256;
        int d = s >> 3, ck = s & 7;
        int kb = (ck >> 2) * 32 + (ck & 3) * 4;
        bf16x8 o;
#pragma unroll
        for (int J = 0; J < 8; J++) o[J] = T[d][kb + (J & 3) + (J >> 2) * 16];
        *(bf16x8*)&dst[(size_t)d * Lc + t * 64 + ck * 8] = o;
    }
}

// ---------------- bf16 MFMA GEMM, DMA-staged ---------------------------------------
// A bf16 [M][768], Bt bf16 [N][768]. Staging via global_load_lds into unpadded
// XOR-chunk-swizzled [128][64] tiles (2-way only = free). m97 2-barrier K-loop.
// mode 0: writes compact Qc(scaled)/Kc/Vc via LDS-transposed coalesced stores.
// mode 1: writes f32 Co + bias directly.
__global__ __launch_bounds__(256, 2) void gemm_kernel(
    const __bf16* __restrict__ Ab, const __bf16* __restrict__ Bt,
    const float* __restrict__ bias,
    __bf16* __restrict__ Qc, __bf16* __restrict__ Kc, __bf16* __restrict__ Vc,
    float* __restrict__ Co, int mode) {
    __shared__ __align__(16) char smem[34816];  // staging 32 KB; T tile 34 KB (reuse)
    __bf16* Al = (__bf16*)smem;                 // [128][64] swizzled
    __bf16* Bl = Al + 128 * 64;
    __bf16* T  = (__bf16*)smem;                 // [128][136] epilogue tile
    int tid = threadIdx.x;
    int wave = tid >> 6, lane = tid & 63;
    int quad = lane >> 4, l15 = lane & 15;
    int bm = blockIdx.x * 128, bn = blockIdx.y * 128;
    int wm = (wave >> 1) * 64, wn = (wave & 1) * 64;
    // DMA slot decode: slot s (0..1023 per operand) -> row s>>3, chunk (s&7)^(row&7)
    int swzA = tid & 7;        // lane's chunk-pos within its row group
    f32x4 acc[4][4] = {};
    for (int k0 = 0; k0 < 768; k0 += 64) {
        __syncthreads();
#pragma unroll
        for (int j = 0; j < 4; j++) {
            int s = j * 256 + tid;
            int row = s >> 3;
            int ch = swzA ^ (row & 7);
            gl2lds16(&Ab[(size_t)(bm + row) * 768 + k0 + ch * 8],
                     (char*)smem + j * 4096 + wave * 1024);
            gl2lds16(&Bt[(size_t)(bn + row) * 768 + k0 + ch * 8],
                     (char*)smem + 16384 + j * 4096 + wave * 1024);
        }
        __syncthreads();
#pragma unroll
        for (int ks = 0; ks < 2; ks++) {
            bf16x8 af[4], bfr[4];
#pragma unroll
            for (int i = 0; i < 4; i++) {
                int row = wm + i * 16 + l15;
                af[i] = *(const bf16x8*)&Al[row * 64 + (((ks * 4 + quad) ^ (row & 7)) * 8)];
            }
#pragma unroll
            for (int j = 0; j < 4; j++) {
                int row = wn + j * 16 + l15;
                bfr[j] = *(const bf16x8*)&Bl[row * 64 + (((ks * 4 + quad) ^ (row & 7)) * 8)];
            }
#pragma unroll
            for (int i = 0; i < 4; i++)
#pragma unroll
                for (int j = 0; j < 4; j++)
                    acc[i][j] = MFMA_BF16(af[i], bfr[j], acc[i][j]);
        }
    }
    if (mode == 0) {
        int which = blockIdx.y / 6;             // uniform: 0=Q 1=K 2=V
        int h0 = (blockIdx.y % 6) * 2;          // first head of this 128-col block
        float scl = which == 0 ? QSCALE : 1.0f;
        float bv[4];
#pragma unroll
        for (int j = 0; j < 4; j++) bv[j] = bias[bn + wn + j * 16 + l15];
        __syncthreads();  // done reading Al/Bl
#pragma unroll
        for (int i = 0; i < 4; i++)
#pragma unroll
            for (int j = 0; j < 4; j++) {
                int col = wn + j * 16 + l15;
#pragma unroll
                for (int r = 0; r < 4; r++) {
                    int row = wm + i * 16 + quad * 4 + r;
                    int ch = ((col >> 3) & 8) | (((col >> 3) & 7) ^ (row & 7));
                    T[row * 136 + ch * 8 + (col & 7)] =
                        (__bf16)((acc[i][j][r] + bv[j]) * scl);
                }
            }
        __syncthreads();
        __bf16* dst = which == 0 ? Qc : (which == 1 ? Kc : Vc);
        int rr = tid >> 4;        // 0..15
        int c8 = tid & 15;        // 0..15
        int hh = c8 >> 3, d8 = c8 & 7;
        int h = h0 + hh;
        __bf16* p0 = dst + ((size_t)h * 2048 * 64) + d8 * 8;
        __bf16* p1 = dst + SEG1OFF + ((size_t)h * 4096 * 64) + d8 * 8;
        __bf16* p2 = dst + SEG2OFF + ((size_t)h * 2048 * 64) + d8 * 8;
#pragma unroll
        for (int pass = 0; pass < 8; pass++) {
            int row = pass * 16 + rr;
            int pos = bm + row;
            int ch = (c8 & 8) | ((c8 & 7) ^ (row & 7));
            bf16x8 v = *(const bf16x8*)&T[row * 136 + ch * 8];
            if (pos < 2048) *(bf16x8*)&p0[(size_t)pos * 64] = v;
            if (!(pos & 1)) *(bf16x8*)&p1[(size_t)(pos >> 1) * 64] = v;
            if (!(pos & 3)) *(bf16x8*)&p2[(size_t)(pos >> 2) * 64] = v;
        }
    } else {
        int quad4 = quad * 4;
#pragma unroll
        for (int j = 0; j < 4; j++) {
            int c = bn + wn + j * 16 + l15;
            float bv = bias[c];
#pragma unroll
            for (int i = 0; i < 4; i++)
#pragma unroll
                for (int r = 0; r < 4; r++) {
                    int row = bm + wm + i * 16 + quad4 + r;
                    Co[(size_t)row * 768 + c] = acc[i][j][r] + bv;
                }
        }
    }
}

// ---------------- fused flash attention, S^T form, no-max softmax, kv-split --------
// 1152 uniform blocks x 32 iters, 256 threads, 32 q/wave (128 q/block).
// Single-buffered DMA staging: with ~4.5 blocks/CU the inter-wave TLP hides the
// drain; dbuf/bigger-q variants (r4/r5) raised VGPR, cut occupancy, and regressed.
__global__ __launch_bounds__(256, 2) void attn_kernel(
    const __bf16* __restrict__ Qcb, const __bf16* __restrict__ Kcb,
    const __bf16* __restrict__ Vtb,
    float* __restrict__ O0, float* __restrict__ O1a, float* __restrict__ O1b,
    float* __restrict__ O2, float* __restrict__ L0, float* __restrict__ L1a,
    float* __restrict__ L1b, float* __restrict__ L2) {
    __shared__ __bf16 Kl[64 * 64];
    __shared__ __bf16 Vl[64 * 64];
    int bid = blockIdx.x;
    int seg, half = 0, head, qt, Lc;
    if (bid < 768)      { int i = bid >> 1; half = bid & 1; head = i >> 5; qt = i & 31; Lc = 4096; seg = 1; }
    else if (bid < 960) { int i = bid - 768; head = i >> 4; qt = i & 15; Lc = 2048; seg = 0; }
    else                { int i = bid - 960; head = i >> 4; qt = i & 15; Lc = 2048; seg = 2; }
    size_t soff = seg == 0 ? 0 : (seg == 1 ? SEG1OFF : SEG2OFF);
    const __bf16* Qh = Qcb + soff + (size_t)head * Lc * 64;
    const __bf16* Kh = Kcb + soff + (size_t)head * Lc * 64;
    const __bf16* Vh = Vtb + soff + (size_t)head * 64 * Lc;
    float* Ob;
    float* Lb;
    if (seg == 0)      { Ob = O0; Lb = L0 + head * 2048; }
    else if (seg == 1) { Ob = half ? O1b : O1a; Lb = (half ? L1b : L1a) + head * 4096; }
    else               { Ob = O2; Lb = L2 + head * 2048; }
    int kvb = (seg == 1) ? half * 32 : 0;
    int tid = threadIdx.x, wave = tid >> 6, lane = tid & 63;
    int quad = lane >> 4, l15 = lane & 15;
    bf16x8 qf[2][2];
#pragma unroll
    for (int qg = 0; qg < 2; qg++) {
        size_t qpos = (size_t)(qt * 128 + wave * 32 + qg * 16 + l15);
        qf[qg][0] = *(const bf16x8*)&Qh[qpos * 64 + quad * 8];
        qf[qg][1] = *(const bf16x8*)&Qh[qpos * 64 + 32 + quad * 8];
    }
    f32x4 o[2][4] = {};
    float lrun[2] = {0.f, 0.f};
    int kv0 = tid >> 3, cl0 = tid & 7;
    int kdb0 = cl0 ^ (kv0 & 7);
    int kv1 = kv0 + 32, kdb1 = cl0 ^ (kv1 & 7);
    char* KlB = (char*)Kl;
    char* VlB = (char*)Vl;
    int swz = l15 & 7;
    for (int nt = 0; nt < 32; nt++) {
        int t0 = (kvb + nt) * 64;
        __syncthreads();
        gl2lds16(&Kh[(size_t)(t0 + kv0) * 64 + kdb0 * 8], KlB + wave * 1024);
        gl2lds16(&Kh[(size_t)(t0 + kv1) * 64 + kdb1 * 8], KlB + 4096 + wave * 1024);
        gl2lds16(&Vh[(size_t)kv0 * Lc + t0 + kdb0 * 8], VlB + wave * 1024);
        gl2lds16(&Vh[(size_t)kv1 * Lc + t0 + kdb1 * 8], VlB + 4096 + wave * 1024);
        __syncthreads();
        f32x4 sarr[4][2];
#pragma unroll
        for (int c = 0; c < 4; c++) {
            int krow = (c * 16 + l15) * 64;
            bf16x8 kf0 = *(const bf16x8*)&Kl[krow + ((quad ^ swz) * 8)];
            bf16x8 kf1 = *(const bf16x8*)&Kl[krow + (((4 + quad) ^ swz) * 8)];
#pragma unroll
            for (int qg = 0; qg < 2; qg++) {
                f32x4 z = {};
                z = MFMA_BF16(kf0, qf[qg][0], z);
                sarr[c][qg] = MFMA_BF16(kf1, qf[qg][1], z);
            }
        }
        bf16x8 pf8[2][2];
#pragma unroll
        for (int qg = 0; qg < 2; qg++)
#pragma unroll
            for (int c = 0; c < 4; c++)
#pragma unroll
                for (int r = 0; r < 4; r++) {
                    float p = fexp2(sarr[c][qg][r]);
                    lrun[qg] += p;
                    pf8[qg][c >> 1][(c & 1) * 4 + r] = (__bf16)p;
                }
#pragma unroll
        for (int u = 0; u < 2; u++)
#pragma unroll
            for (int ds = 0; ds < 4; ds++) {
                int d = ds * 16 + l15;
                bf16x8 vf = *(const bf16x8*)&Vl[d * 64 + (((u * 4 + quad) ^ swz) * 8)];
                o[0][ds] = MFMA_BF16(vf, pf8[0][u], o[0][ds]);
                o[1][ds] = MFMA_BF16(vf, pf8[1][u], o[1][ds]);
            }
    }
#pragma unroll
    for (int qg = 0; qg < 2; qg++) {
        float l = lrun[qg];
        l += __shfl_xor(l, 16, 64);
        l += __shfl_xor(l, 32, 64);
        int pos = qt * 128 + wave * 32 + qg * 16 + l15;
        float* orow = Ob + (size_t)pos * 768 + head * 64;
#pragma unroll
        for (int ds = 0; ds < 4; ds++)
            *(f32x4*)&orow[ds * 16 + quad * 4] = o[qg][ds];
        if (lane < 16) Lb[qt * 128 + wave * 32 + qg * 16 + lane] = l;
    }
}

// ---------------- combine: attnF[q][768] = (1/3) * sum_seg O_seg/l_seg, bf16 -------
__global__ __launch_bounds__(256) void combine_kernel(
    const float* __restrict__ O0, const float* __restrict__ O1a,
    const float* __restrict__ O1b, const float* __restrict__ O2,
    const float* __restrict__ L0, const float* __restrict__ L1a,
    const float* __restrict__ L1b, const float* __restrict__ L2,
    __bf16* __restrict__ attnF) {
    int g = blockIdx.x * 256 + threadIdx.x;  // 8192*96
    int q = g / 96;
    int cs = (g - q * 96) * 8;
    int head = cs >> 6;
    f32x4 a0 = {}, a1 = {};
    if (q < 2048) {
        float inv = 1.0f / L0[head * 2048 + q];
        const f32x4* p = (const f32x4*)&O0[(size_t)q * 768 + cs];
        a0 += p[0] * inv; a1 += p[1] * inv;
    }
    if (!(q & 1)) {
        int p1 = q >> 1;
        float inv = 1.0f / (L1a[head * 4096 + p1] + L1b[head * 4096 + p1]);
        const f32x4* pa = (const f32x4*)&O1a[(size_t)p1 * 768 + cs];
        const f32x4* pb = (const f32x4*)&O1b[(size_t)p1 * 768 + cs];
        a0 += (pa[0] + pb[0]) * inv; a1 += (pa[1] + pb[1]) * inv;
    }
    if (!(q & 3)) {
        int p2 = q >> 2;
        float inv = 1.0f / L2[head * 2048 + p2];
        const f32x4* p = (const f32x4*)&O2[(size_t)p2 * 768 + cs];
        a0 += p[0] * inv; a1 += p[1] * inv;
    }
    const float third = 1.0f / 3.0f;
    bf16x8 ov;
    ov[0] = (__bf16)(a0[0] * third); ov[1] = (__bf16)(a0[1] * third);
    ov[2] = (__bf16)(a0[2] * third); ov[3] = (__bf16)(a0[3] * third);
    ov[4] = (__bf16)(a1[0] * third); ov[5] = (__bf16)(a1[1] * third);
    ov[6] = (__bf16)(a1[2] * third); ov[7] = (__bf16)(a1[3] * third);
    *(bf16x8*)&attnF[(size_t)q * 768 + cs] = ov;
}

extern "C" void kernel_launch(void* const* d_in, const int* in_sizes, int n_in,
                              void* d_out, int out_size, void* d_ws, size_t ws_size,
                              hipStream_t stream) {
    const float* x    = (const float*)d_in[0];
    const float* Wqkv = (const float*)d_in[1];
    const float* bqkv = (const float*)d_in[2];
    const float* Wout = (const float*)d_in[3];
    const float* bout = (const float*)d_in[4];
    float* out = (float*)d_out;
    (void)in_sizes; (void)n_in; (void)out_size; (void)ws_size;

    char* ws = (char*)d_ws;
    size_t off = 0;
    auto take = [&](size_t bytes) -> void* {
        void* p = ws + off;
        off += (bytes + 255) & ~(size_t)255;
        return p;
    };
    const size_t QKV_ELEMS = (size_t)12 * 8192 * 64;  // compact seg-major total
    __bf16* xb    = (__bf16*)take((size_t)8192 * 768 * 2);
    __bf16* WqkvT = (__bf16*)take((size_t)2304 * 768 * 2);
    __bf16* WoutT = (__bf16*)take((size_t)768 * 768 * 2);
    __bf16* Qc    = (__bf16*)take(QKV_ELEMS * 2);
    __bf16* Kc    = (__bf16*)take(QKV_ELEMS * 2);
    __bf16* Vc    = (__bf16*)take(QKV_ELEMS * 2);
    __bf16* Vt    = (__bf16*)take(QKV_ELEMS * 2);
    float*  O0    = (float*)take((size_t)2048 * 768 * 4);
    float*  O1a   = (float*)take((size_t)4096 * 768 * 4);
    float*  O1b   = (float*)take((size_t)4096 * 768 * 4);
    float*  O2    = (float*)take((size_t)2048 * 768 * 4);
    float*  L0    = (float*)take((size_t)12 * 2048 * 4);
    float*  L1a   = (float*)take((size_t)12 * 4096 * 4);
    float*  L1b   = (float*)take((size_t)12 * 4096 * 4);
    float*  L2    = (float*)take((size_t)12 * 2048 * 4);
    __bf16* attnF = Qc;  // alias: Qc dead after attn_kernel

    cvt_kernel<<<3072, 256, 0, stream>>>(x, xb, 8192 * 768 / 8);
    transpose_cvt_kernel<<<dim3(9, 96), 256, 0, stream>>>(Wqkv, WqkvT, 2304);
    transpose_cvt_kernel<<<dim3(3, 96), 256, 0, stream>>>(Wout, WoutT, 768);
    gemm_kernel<<<dim3(64, 18), 256, 0, stream>>>(xb, WqkvT, bqkv, Qc, Kc, Vc,
                                                  nullptr, 0);
    vtrans_kernel<<<1536, 256, 0, stream>>>(Vc, Vt);
    attn_kernel<<<1152, 256, 0, stream>>>(Qc, Kc, Vt, O0, O1a, O1b, O2, L0, L1a, L1b, L2);
    combine_kernel<<<3072, 256, 0, stream>>>(O0, O1a, O1b, O2, L0, L1a, L1b, L2, attnF);
    gemm_kernel<<<dim3(64, 6), 256, 0, stream>>>(attnF, WoutT, bout, nullptr, nullptr,
                                                 nullptr, out, 1);
}

// Round 7
// 254.896 us; speedup vs baseline: 1.2995x; 1.0187x over previous
//
#include <hip/hip_runtime.h>
#include <hip/hip_bf16.h>

typedef float f32x4 __attribute__((ext_vector_type(4)));
typedef float fvec4 __attribute__((ext_vector_type(4)));
typedef __bf16 bf16x8 __attribute__((ext_vector_type(8)));
typedef __bf16 bf16x2 __attribute__((ext_vector_type(2)));

__device__ inline float fexp2(float x) {
#if __has_builtin(__builtin_amdgcn_exp2f)
    return __builtin_amdgcn_exp2f(x);
#else
    return exp2f(x);
#endif
}

// packed f32x2 -> bf16x2 (single v_cvt_pk_bf16_f32 when available)
__device__ __forceinline__ bf16x2 pk_bf16(float a, float b) {
#if __has_builtin(__builtin_amdgcn_cvt_pk_bf16_f32)
    auto t = __builtin_amdgcn_cvt_pk_bf16_f32(a, b);
    return __builtin_bit_cast(bf16x2, t);
#else
    bf16x2 r; r[0] = (__bf16)a; r[1] = (__bf16)b; return r;
#endif
}

#define MFMA_BF16(a, b, c) __builtin_amdgcn_mfma_f32_16x16x32_bf16((a), (b), (c), 0, 0, 0)

__device__ __forceinline__ void gl2lds16(const void* g, void* l) {
    __builtin_amdgcn_global_load_lds((const __attribute__((address_space(1))) void*)g,
                                     (__attribute__((address_space(3))) void*)l, 16, 0, 0);
}

// seg offsets (elements) inside compact Q/K/V buffers: [seg0 12x2048][seg1 12x4096][seg2 12x2048] x64d
#define SEG1OFF ((size_t)12 * 2048 * 64)
#define SEG2OFF ((size_t)12 * 6144 * 64)
#define QSCALE 0.18033688f  // SCALE * log2(e)

// ---------------- f32 -> bf16 elementwise convert (8 elems/thread) ----------------
__global__ __launch_bounds__(256) void cvt_kernel(const float* __restrict__ in,
                                                  __bf16* __restrict__ out, int n8) {
    int i = blockIdx.x * 256 + threadIdx.x;
    if (i >= n8) return;
    fvec4 a = ((const fvec4*)in)[2 * i];
    fvec4 b = ((const fvec4*)in)[2 * i + 1];
    bf16x8 o;
    o[0] = (__bf16)a[0]; o[1] = (__bf16)a[1]; o[2] = (__bf16)a[2]; o[3] = (__bf16)a[3];
    o[4] = (__bf16)b[0]; o[5] = (__bf16)b[1]; o[6] = (__bf16)b[2]; o[7] = (__bf16)b[3];
    ((bf16x8*)out)[i] = o;
}

// ---------------- W [K=768][N] f32 -> Wt [N][768] bf16 ----------------------------
__global__ __launch_bounds__(256) void transpose_cvt_kernel(const float* __restrict__ src,
                                                            __bf16* __restrict__ dst, int N) {
    int n = blockIdx.x * 256 + threadIdx.x;
    int kg = blockIdx.y;
    if (n >= N) return;
    bf16x8 o;
#pragma unroll
    for (int j = 0; j < 8; j++) o[j] = (__bf16)src[(size_t)(kg * 8 + j) * N + n];
    *(bf16x8*)&dst[(size_t)n * 768 + kg * 8] = o;
}

// ---- Vc compact [seg][head][pos][64] -> Vt [seg][head][64][Lc] in MFMA-k order ----
__global__ __launch_bounds__(256) void vtrans_kernel(const __bf16* __restrict__ Vc,
                                                     __bf16* __restrict__ Vt) {
    __shared__ __bf16 T[64][68];
    int bid = blockIdx.x;
    int Lc, head, t;
    size_t soff;
    if (bid < 768)       { Lc = 4096; head = bid >> 6; t = bid & 63; soff = SEG1OFF; }
    else if (bid < 1152) { int i = bid - 768; Lc = 2048; head = i >> 5; t = i & 31; soff = 0; }
    else                 { int i = bid - 1152; Lc = 2048; head = i >> 5; t = i & 31; soff = SEG2OFF; }
    const __bf16* src = Vc + soff + (size_t)head * Lc * 64;
    __bf16* dst = Vt + soff + (size_t)head * 64 * Lc;
    int tid = threadIdx.x;
#pragma unroll
    for (int it = 0; it < 2; it++) {
        int s = tid + it * 256;
        int kvr = s >> 3, d8 = (s & 7) * 8;
        bf16x8 vv = *(const bf16x8*)&src[(size_t)(t * 64 + kvr) * 64 + d8];
#pragma unroll
        for (int j = 0; j < 8; j++) T[d8 + j][kvr] = vv[j];
    }
    __syncthreads();
#pragma unroll
    for (int it = 0; it < 2; it++) {
        int s = tid + it * 256;
        int d = s >> 3, ck = s & 7;
        int kb = (ck >> 2) * 32 + (ck & 3) * 4;
        bf16x8 o;
#pragma unroll
        for (int J = 0; J < 8; J++) o[J] = T[d][kb + (J & 3) + (J >> 2) * 16];
        *(bf16x8*)&dst[(size_t)d * Lc + t * 64 + ck * 8] = o;
    }
}

// ---------------- QKV GEMM: [8192][768] x [2304][768]^T, DMA-staged ---------------
// Writes compact Qc(scaled)/Kc/Vc via LDS-transposed coalesced stores.
__global__ __launch_bounds__(256, 2) void gemm_qkv_kernel(
    const __bf16* __restrict__ Ab, const __bf16* __restrict__ Bt,
    const float* __restrict__ bias,
    __bf16* __restrict__ Qc, __bf16* __restrict__ Kc, __bf16* __restrict__ Vc) {
    __shared__ __align__(16) char smem[34816];  // staging 32 KB; T tile 34 KB (reuse)
    __bf16* Al = (__bf16*)smem;                 // [128][64] swizzled
    __bf16* Bl = Al + 128 * 64;
    __bf16* T  = (__bf16*)smem;                 // [128][136] epilogue tile
    int tid = threadIdx.x;
    int wave = tid >> 6, lane = tid & 63;
    int quad = lane >> 4, l15 = lane & 15;
    int bm = blockIdx.x * 128, bn = blockIdx.y * 128;
    int wm = (wave >> 1) * 64, wn = (wave & 1) * 64;
    int swzA = tid & 7;
    f32x4 acc[4][4] = {};
    for (int k0 = 0; k0 < 768; k0 += 64) {
        __syncthreads();
#pragma unroll
        for (int j = 0; j < 4; j++) {
            int s = j * 256 + tid;
            int row = s >> 3;
            int ch = swzA ^ (row & 7);
            gl2lds16(&Ab[(size_t)(bm + row) * 768 + k0 + ch * 8],
                     (char*)smem + j * 4096 + wave * 1024);
            gl2lds16(&Bt[(size_t)(bn + row) * 768 + k0 + ch * 8],
                     (char*)smem + 16384 + j * 4096 + wave * 1024);
        }
        __syncthreads();
#pragma unroll
        for (int ks = 0; ks < 2; ks++) {
            bf16x8 af[4], bfr[4];
#pragma unroll
            for (int i = 0; i < 4; i++) {
                int row = wm + i * 16 + l15;
                af[i] = *(const bf16x8*)&Al[row * 64 + (((ks * 4 + quad) ^ (row & 7)) * 8)];
            }
#pragma unroll
            for (int j = 0; j < 4; j++) {
                int row = wn + j * 16 + l15;
                bfr[j] = *(const bf16x8*)&Bl[row * 64 + (((ks * 4 + quad) ^ (row & 7)) * 8)];
            }
#pragma unroll
            for (int i = 0; i < 4; i++)
#pragma unroll
                for (int j = 0; j < 4; j++)
                    acc[i][j] = MFMA_BF16(af[i], bfr[j], acc[i][j]);
        }
    }
    int which = blockIdx.y / 6;             // uniform: 0=Q 1=K 2=V
    int h0 = (blockIdx.y % 6) * 2;          // first head of this 128-col block
    float scl = which == 0 ? QSCALE : 1.0f;
    float bv[4];
#pragma unroll
    for (int j = 0; j < 4; j++) bv[j] = bias[bn + wn + j * 16 + l15];
    __syncthreads();  // done reading Al/Bl
#pragma unroll
    for (int i = 0; i < 4; i++)
#pragma unroll
        for (int j = 0; j < 4; j++) {
            int col = wn + j * 16 + l15;
#pragma unroll
            for (int r = 0; r < 4; r++) {
                int row = wm + i * 16 + quad * 4 + r;
                int ch = ((col >> 3) & 8) | (((col >> 3) & 7) ^ (row & 7));
                T[row * 136 + ch * 8 + (col & 7)] =
                    (__bf16)((acc[i][j][r] + bv[j]) * scl);
            }
        }
    __syncthreads();
    __bf16* dst = which == 0 ? Qc : (which == 1 ? Kc : Vc);
    int rr = tid >> 4;        // 0..15
    int c8 = tid & 15;        // 0..15
    int hh = c8 >> 3, d8 = c8 & 7;
    int h = h0 + hh;
    __bf16* p0 = dst + ((size_t)h * 2048 * 64) + d8 * 8;
    __bf16* p1 = dst + SEG1OFF + ((size_t)h * 4096 * 64) + d8 * 8;
    __bf16* p2 = dst + SEG2OFF + ((size_t)h * 2048 * 64) + d8 * 8;
#pragma unroll
    for (int pass = 0; pass < 8; pass++) {
        int row = pass * 16 + rr;
        int pos = bm + row;
        int ch = (c8 & 8) | ((c8 & 7) ^ (row & 7));
        bf16x8 v = *(const bf16x8*)&T[row * 136 + ch * 8];
        if (pos < 2048) *(bf16x8*)&p0[(size_t)pos * 64] = v;
        if (!(pos & 1)) *(bf16x8*)&p1[(size_t)(pos >> 1) * 64] = v;
        if (!(pos & 3)) *(bf16x8*)&p2[(size_t)(pos >> 2) * 64] = v;
    }
}

// ---------------- out-proj GEMM: 64x128 tiles for occupancy (768 blocks) ----------
__global__ __launch_bounds__(256) void gemm_out_kernel(
    const __bf16* __restrict__ Ab, const __bf16* __restrict__ Bt,
    const float* __restrict__ bias, float* __restrict__ Co) {
    __shared__ __align__(16) char smem[24576];
    __bf16* Al = (__bf16*)smem;           // [64][64] swizzled  (8 KB)
    __bf16* Bl = Al + 64 * 64;            // [128][64] swizzled (16 KB)
    int tid = threadIdx.x;
    int wave = tid >> 6, lane = tid & 63;
    int quad = lane >> 4, l15 = lane & 15;
    int bm = blockIdx.x * 64, bn = blockIdx.y * 128;
    int wn = wave * 32;
    f32x4 acc[4][2] = {};
    for (int k0 = 0; k0 < 768; k0 += 64) {
        __syncthreads();
#pragma unroll
        for (int j = 0; j < 2; j++) {
            int s = j * 256 + tid;
            int row = s >> 3;
            int ch = (s & 7) ^ (row & 7);
            gl2lds16(&Ab[(size_t)(bm + row) * 768 + k0 + ch * 8],
                     (char*)smem + j * 4096 + wave * 1024);
        }
#pragma unroll
        for (int j = 0; j < 4; j++) {
            int s = j * 256 + tid;
            int row = s >> 3;
            int ch = (s & 7) ^ (row & 7);
            gl2lds16(&Bt[(size_t)(bn + row) * 768 + k0 + ch * 8],
                     (char*)smem + 8192 + j * 4096 + wave * 1024);
        }
        __syncthreads();
#pragma unroll
        for (int ks = 0; ks < 2; ks++) {
            bf16x8 af[4], bfr[2];
#pragma unroll
            for (int i = 0; i < 4; i++) {
                int row = i * 16 + l15;
                af[i] = *(const bf16x8*)&Al[row * 64 + (((ks * 4 + quad) ^ (row & 7)) * 8)];
            }
#pragma unroll
            for (int j = 0; j < 2; j++) {
                int row = wn + j * 16 + l15;
                bfr[j] = *(const bf16x8*)&Bl[row * 64 + (((ks * 4 + quad) ^ (row & 7)) * 8)];
            }
#pragma unroll
            for (int i = 0; i < 4; i++)
#pragma unroll
                for (int j = 0; j < 2; j++)
                    acc[i][j] = MFMA_BF16(af[i], bfr[j], acc[i][j]);
        }
    }
#pragma unroll
    for (int j = 0; j < 2; j++) {
        int c = bn + wn + j * 16 + l15;
        float bv = bias[c];
#pragma unroll
        for (int i = 0; i < 4; i++)
#pragma unroll
            for (int r = 0; r < 4; r++) {
                int row = bm + i * 16 + quad * 4 + r;
                Co[(size_t)row * 768 + c] = acc[i][j][r] + bv;
            }
    }
}

// ---------------- fused flash attention, S^T form, no-max softmax ------------------
// 1920 blocks: seg0/seg2 (32 iters) first, then seg1 split into 4 kv-quarters
// (16 iters) -> ~7.5 blocks/CU, long blocks start first so the tail is short ones.
// Inner loop identical to the verified r3/r6 kernel (60 VGPR, 0 conflicts).
__global__ __launch_bounds__(256, 2) void attn_kernel(
    const __bf16* __restrict__ Qcb, const __bf16* __restrict__ Kcb,
    const __bf16* __restrict__ Vtb,
    float* __restrict__ O0, float* __restrict__ O1a, float* __restrict__ O1b,
    float* __restrict__ O1c, float* __restrict__ O1d, float* __restrict__ O2,
    float* __restrict__ L0, float* __restrict__ L1a, float* __restrict__ L1b,
    float* __restrict__ L1c, float* __restrict__ L1d, float* __restrict__ L2) {
    __shared__ __bf16 Kl[64 * 64];
    __shared__ __bf16 Vl[64 * 64];
    int bid = blockIdx.x;
    int seg, piece = 0, head, qt, Lc, iters;
    if (bid < 192)      { seg = 0; head = bid >> 4; qt = bid & 15; Lc = 2048; iters = 32; }
    else if (bid < 384) { int i = bid - 192; seg = 2; head = i >> 4; qt = i & 15; Lc = 2048; iters = 32; }
    else                { int i = bid - 384; seg = 1; head = i >> 7; int r = i & 127;
                          qt = r >> 2; piece = r & 3; Lc = 4096; iters = 16; }
    size_t soff = seg == 0 ? 0 : (seg == 1 ? SEG1OFF : SEG2OFF);
    const __bf16* Qh = Qcb + soff + (size_t)head * Lc * 64;
    const __bf16* Kh = Kcb + soff + (size_t)head * Lc * 64;
    const __bf16* Vh = Vtb + soff + (size_t)head * 64 * Lc;
    float* Ob;
    float* Lb;
    if (seg == 0)      { Ob = O0; Lb = L0 + head * 2048; }
    else if (seg == 2) { Ob = O2; Lb = L2 + head * 2048; }
    else {
        Ob = piece == 0 ? O1a : (piece == 1 ? O1b : (piece == 2 ? O1c : O1d));
        Lb = (piece == 0 ? L1a : (piece == 1 ? L1b : (piece == 2 ? L1c : L1d))) + head * 4096;
    }
    int kvb = piece * 16;
    int tid = threadIdx.x, wave = tid >> 6, lane = tid & 63;
    int quad = lane >> 4, l15 = lane & 15;
    bf16x8 qf[2][2];
#pragma unroll
    for (int qg = 0; qg < 2; qg++) {
        size_t qpos = (size_t)(qt * 128 + wave * 32 + qg * 16 + l15);
        qf[qg][0] = *(const bf16x8*)&Qh[qpos * 64 + quad * 8];
        qf[qg][1] = *(const bf16x8*)&Qh[qpos * 64 + 32 + quad * 8];
    }
    f32x4 o[2][4] = {};
    float lrun[2] = {0.f, 0.f};
    int kv0 = tid >> 3, cl0 = tid & 7;
    int kdb0 = cl0 ^ (kv0 & 7);
    int kv1 = kv0 + 32, kdb1 = cl0 ^ (kv1 & 7);
    char* KlB = (char*)Kl;
    char* VlB = (char*)Vl;
    int swz = l15 & 7;
    for (int nt = 0; nt < iters; nt++) {
        int t0 = (kvb + nt) * 64;
        __syncthreads();
        gl2lds16(&Kh[(size_t)(t0 + kv0) * 64 + kdb0 * 8], KlB + wave * 1024);
        gl2lds16(&Kh[(size_t)(t0 + kv1) * 64 + kdb1 * 8], KlB + 4096 + wave * 1024);
        gl2lds16(&Vh[(size_t)kv0 * Lc + t0 + kdb0 * 8], VlB + wave * 1024);
        gl2lds16(&Vh[(size_t)kv1 * Lc + t0 + kdb1 * 8], VlB + 4096 + wave * 1024);
        __syncthreads();
        f32x4 sarr[4][2];
#pragma unroll
        for (int c = 0; c < 4; c++) {
            int krow = (c * 16 + l15) * 64;
            bf16x8 kf0 = *(const bf16x8*)&Kl[krow + ((quad ^ swz) * 8)];
            bf16x8 kf1 = *(const bf16x8*)&Kl[krow + (((4 + quad) ^ swz) * 8)];
#pragma unroll
            for (int qg = 0; qg < 2; qg++) {
                f32x4 z = {};
                z = MFMA_BF16(kf0, qf[qg][0], z);
                sarr[c][qg] = MFMA_BF16(kf1, qf[qg][1], z);
            }
        }
        union { bf16x8 v8; bf16x2 v2[4]; } pf8[2][2];
#pragma unroll
        for (int qg = 0; qg < 2; qg++)
#pragma unroll
            for (int c = 0; c < 4; c++) {
                float p0 = fexp2(sarr[c][qg][0]);
                float p1 = fexp2(sarr[c][qg][1]);
                float p2 = fexp2(sarr[c][qg][2]);
                float p3 = fexp2(sarr[c][qg][3]);
                lrun[qg] += (p0 + p1) + (p2 + p3);
                pf8[qg][c >> 1].v2[(c & 1) * 2 + 0] = pk_bf16(p0, p1);
                pf8[qg][c >> 1].v2[(c & 1) * 2 + 1] = pk_bf16(p2, p3);
            }
#pragma unroll
        for (int u = 0; u < 2; u++)
#pragma unroll
            for (int ds = 0; ds < 4; ds++) {
                int d = ds * 16 + l15;
                bf16x8 vf = *(const bf16x8*)&Vl[d * 64 + (((u * 4 + quad) ^ swz) * 8)];
                o[0][ds] = MFMA_BF16(vf, pf8[0][u].v8, o[0][ds]);
                o[1][ds] = MFMA_BF16(vf, pf8[1][u].v8, o[1][ds]);
            }
    }
#pragma unroll
    for (int qg = 0; qg < 2; qg++) {
        float l = lrun[qg];
        l += __shfl_xor(l, 16, 64);
        l += __shfl_xor(l, 32, 64);
        int pos = qt * 128 + wave * 32 + qg * 16 + l15;
        float* orow = Ob + (size_t)pos * 768 + head * 64;
#pragma unroll
        for (int ds = 0; ds < 4; ds++)
            *(f32x4*)&orow[ds * 16 + quad * 4] = o[qg][ds];
        if (lane < 16) Lb[qt * 128 + wave * 32 + qg * 16 + lane] = l;
    }
}

// ---------------- combine: attnF[q][768] = (1/3) * sum_seg O_seg/l_seg, bf16 -------
__global__ __launch_bounds__(256) void combine_kernel(
    const float* __restrict__ O0, const float* __restrict__ O1a,
    const float* __restrict__ O1b, const float* __restrict__ O1c,
    const float* __restrict__ O1d, const float* __restrict__ O2,
    const float* __restrict__ L0, const float* __restrict__ L1a,
    const float* __restrict__ L1b, const float* __restrict__ L1c,
    const float* __restrict__ L1d, const float* __restrict__ L2,
    __bf16* __restrict__ attnF) {
    int g = blockIdx.x * 256 + threadIdx.x;  // 8192*96
    int q = g / 96;
    int cs = (g - q * 96) * 8;
    int head = cs >> 6;
    f32x4 a0 = {}, a1 = {};
    if (q < 2048) {
        float inv = 1.0f / L0[head * 2048 + q];
        const f32x4* p = (const f32x4*)&O0[(size_t)q * 768 + cs];
        a0 += p[0] * inv; a1 += p[1] * inv;
    }
    if (!(q & 1)) {
        int p1 = q >> 1;
        int li = head * 4096 + p1;
        float inv = 1.0f / (L1a[li] + L1b[li] + L1c[li] + L1d[li]);
        size_t ro = (size_t)p1 * 768 + cs;
        const f32x4* pa = (const f32x4*)&O1a[ro];
        const f32x4* pb = (const f32x4*)&O1b[ro];
        const f32x4* pc = (const f32x4*)&O1c[ro];
        const f32x4* pd = (const f32x4*)&O1d[ro];
        a0 += ((pa[0] + pb[0]) + (pc[0] + pd[0])) * inv;
        a1 += ((pa[1] + pb[1]) + (pc[1] + pd[1])) * inv;
    }
    if (!(q & 3)) {
        int p2 = q >> 2;
        float inv = 1.0f / L2[head * 2048 + p2];
        const f32x4* p = (const f32x4*)&O2[(size_t)p2 * 768 + cs];
        a0 += p[0] * inv; a1 += p[1] * inv;
    }
    const float third = 1.0f / 3.0f;
    bf16x8 ov;
    ov[0] = (__bf16)(a0[0] * third); ov[1] = (__bf16)(a0[1] * third);
    ov[2] = (__bf16)(a0[2] * third); ov[3] = (__bf16)(a0[3] * third);
    ov[4] = (__bf16)(a1[0] * third); ov[5] = (__bf16)(a1[1] * third);
    ov[6] = (__bf16)(a1[2] * third); ov[7] = (__bf16)(a1[3] * third);
    *(bf16x8*)&attnF[(size_t)q * 768 + cs] = ov;
}

extern "C" void kernel_launch(void* const* d_in, const int* in_sizes, int n_in,
                              void* d_out, int out_size, void* d_ws, size_t ws_size,
                              hipStream_t stream) {
    const float* x    = (const float*)d_in[0];
    const float* Wqkv = (const float*)d_in[1];
    const float* bqkv = (const float*)d_in[2];
    const float* Wout = (const float*)d_in[3];
    const float* bout = (const float*)d_in[4];
    float* out = (float*)d_out;
    (void)in_sizes; (void)n_in; (void)out_size; (void)ws_size;

    char* ws = (char*)d_ws;
    size_t off = 0;
    auto take = [&](size_t bytes) -> void* {
        void* p = ws + off;
        off += (bytes + 255) & ~(size_t)255;
        return p;
    };
    const size_t QKV_ELEMS = (size_t)12 * 8192 * 64;  // compact seg-major total
    __bf16* xb    = (__bf16*)take((size_t)8192 * 768 * 2);  // dead after gemm0 -> O0|O2
    __bf16* WqkvT = (__bf16*)take((size_t)2304 * 768 * 2);
    __bf16* WoutT = (__bf16*)take((size_t)768 * 768 * 2);
    __bf16* Qc    = (__bf16*)take(QKV_ELEMS * 2);           // attnF alias after attn
    __bf16* Kc    = (__bf16*)take(QKV_ELEMS * 2);
    __bf16* Vc    = (__bf16*)take(QKV_ELEMS * 2);           // dead after vtrans -> O1d
    __bf16* Vt    = (__bf16*)take(QKV_ELEMS * 2);
    float*  O1a   = (float*)take((size_t)4096 * 768 * 4);
    float*  O1b   = (float*)take((size_t)4096 * 768 * 4);
    float*  O1c   = (float*)take((size_t)4096 * 768 * 4);
    float*  L0    = (float*)take((size_t)12 * 2048 * 4);
    float*  L1a   = (float*)take((size_t)12 * 4096 * 4);
    float*  L1b   = (float*)take((size_t)12 * 4096 * 4);
    float*  L1c   = (float*)take((size_t)12 * 4096 * 4);
    float*  L1d   = (float*)take((size_t)12 * 4096 * 4);
    float*  L2    = (float*)take((size_t)12 * 2048 * 4);
    float*  O0    = (float*)xb;                 // 2048*768 f32 = 6.29 MB
    float*  O2    = O0 + (size_t)2048 * 768;    // next 6.29 MB (xb is 12.58 MB)
    float*  O1d   = (float*)Vc;                 // 4096*768 f32 = 12.58 MB = |Vc|
    __bf16* attnF = Qc;                         // Qc dead after attn_kernel

    cvt_kernel<<<3072, 256, 0, stream>>>(x, xb, 8192 * 768 / 8);
    transpose_cvt_kernel<<<dim3(9, 96), 256, 0, stream>>>(Wqkv, WqkvT, 2304);
    transpose_cvt_kernel<<<dim3(3, 96), 256, 0, stream>>>(Wout, WoutT, 768);
    gemm_qkv_kernel<<<dim3(64, 18), 256, 0, stream>>>(xb, WqkvT, bqkv, Qc, Kc, Vc);
    vtrans_kernel<<<1536, 256, 0, stream>>>(Vc, Vt);
    attn_kernel<<<1920, 256, 0, stream>>>(Qc, Kc, Vt, O0, O1a, O1b, O1c, O1d, O2,
                                          L0, L1a, L1b, L1c, L1d, L2);
    combine_kernel<<<3072, 256, 0, stream>>>(O0, O1a, O1b, O1c, O1d, O2,
                                             L0, L1a, L1b, L1c, L1d, L2, attnF);
    gemm_out_kernel<<<dim3(128, 6), 256, 0, stream>>>(attnF, WoutT, bout, out);
}

// Round 8
// 243.682 us; speedup vs baseline: 1.3593x; 1.0460x over previous
//
#include <hip/hip_runtime.h>
#include <hip/hip_bf16.h>

typedef float f32x4 __attribute__((ext_vector_type(4)));
typedef float fvec4 __attribute__((ext_vector_type(4)));
typedef __bf16 bf16x8 __attribute__((ext_vector_type(8)));
typedef __bf16 bf16x2 __attribute__((ext_vector_type(2)));

__device__ inline float fexp2(float x) {
#if __has_builtin(__builtin_amdgcn_exp2f)
    return __builtin_amdgcn_exp2f(x);
#else
    return exp2f(x);
#endif
}

// packed f32x2 -> bf16x2 (single v_cvt_pk_bf16_f32 when available)
__device__ __forceinline__ bf16x2 pk_bf16(float a, float b) {
#if __has_builtin(__builtin_amdgcn_cvt_pk_bf16_f32)
    auto t = __builtin_amdgcn_cvt_pk_bf16_f32(a, b);
    return __builtin_bit_cast(bf16x2, t);
#else
    bf16x2 r; r[0] = (__bf16)a; r[1] = (__bf16)b; return r;
#endif
}

#define MFMA_BF16(a, b, c) __builtin_amdgcn_mfma_f32_16x16x32_bf16((a), (b), (c), 0, 0, 0)

__device__ __forceinline__ void gl2lds16(const void* g, void* l) {
    __builtin_amdgcn_global_load_lds((const __attribute__((address_space(1))) void*)g,
                                     (__attribute__((address_space(3))) void*)l, 16, 0, 0);
}

// seg offsets (elements) inside compact Q/K/V buffers: [seg0 12x2048][seg1 12x4096][seg2 12x2048] x64d
#define SEG1OFF ((size_t)12 * 2048 * 64)
#define SEG2OFF ((size_t)12 * 6144 * 64)
#define QSCALE 0.18033688f  // SCALE * log2(e)

// ---------------- fused prep: x->bf16 cvt + both weight transposes ----------------
// blocks [0,3072): cvt x; [3072,3936): Wqkv [768][2304] -> [2304][768];
// [3936,4224): Wout [768][768] -> [768][768] transposed.
__global__ __launch_bounds__(256) void prep_kernel(
    const float* __restrict__ x, const float* __restrict__ Wqkv,
    const float* __restrict__ Wout, __bf16* __restrict__ xb,
    __bf16* __restrict__ WqkvT, __bf16* __restrict__ WoutT) {
    int bid = blockIdx.x, tid = threadIdx.x;
    if (bid < 3072) {
        int i = bid * 256 + tid;
        fvec4 a = ((const fvec4*)x)[2 * i];
        fvec4 b = ((const fvec4*)x)[2 * i + 1];
        bf16x8 o;
        o[0] = (__bf16)a[0]; o[1] = (__bf16)a[1]; o[2] = (__bf16)a[2]; o[3] = (__bf16)a[3];
        o[4] = (__bf16)b[0]; o[5] = (__bf16)b[1]; o[6] = (__bf16)b[2]; o[7] = (__bf16)b[3];
        ((bf16x8*)xb)[i] = o;
    } else if (bid < 3936) {
        int b = bid - 3072;
        int n = (b % 9) * 256 + tid;  // 0..2303
        int kg = b / 9;               // 0..95
        bf16x8 o;
#pragma unroll
        for (int j = 0; j < 8; j++) o[j] = (__bf16)Wqkv[(size_t)(kg * 8 + j) * 2304 + n];
        *(bf16x8*)&WqkvT[(size_t)n * 768 + kg * 8] = o;
    } else {
        int b = bid - 3936;
        int n = (b % 3) * 256 + tid;  // 0..767
        int kg = b / 3;               // 0..95
        bf16x8 o;
#pragma unroll
        for (int j = 0; j < 8; j++) o[j] = (__bf16)Wout[(size_t)(kg * 8 + j) * 768 + n];
        *(bf16x8*)&WoutT[(size_t)n * 768 + kg * 8] = o;
    }
}

// ---- Vc compact [seg][head][pos][64] -> Vt [seg][head][64][Lc] in MFMA-k order ----
__global__ __launch_bounds__(256) void vtrans_kernel(const __bf16* __restrict__ Vc,
                                                     __bf16* __restrict__ Vt) {
    __shared__ __bf16 T[64][68];
    int bid = blockIdx.x;
    int Lc, head, t;
    size_t soff;
    if (bid < 768)       { Lc = 4096; head = bid >> 6; t = bid & 63; soff = SEG1OFF; }
    else if (bid < 1152) { int i = bid - 768; Lc = 2048; head = i >> 5; t = i & 31; soff = 0; }
    else                 { int i = bid - 1152; Lc = 2048; head = i >> 5; t = i & 31; soff = SEG2OFF; }
    const __bf16* src = Vc + soff + (size_t)head * Lc * 64;
    __bf16* dst = Vt + soff + (size_t)head * 64 * Lc;
    int tid = threadIdx.x;
#pragma unroll
    for (int it = 0; it < 2; it++) {
        int s = tid + it * 256;
        int kvr = s >> 3, d8 = (s & 7) * 8;
        bf16x8 vv = *(const bf16x8*)&src[(size_t)(t * 64 + kvr) * 64 + d8];
#pragma unroll
        for (int j = 0; j < 8; j++) T[d8 + j][kvr] = vv[j];
    }
    __syncthreads();
#pragma unroll
    for (int it = 0; it < 2; it++) {
        int s = tid + it * 256;
        int d = s >> 3, ck = s & 7;
        int kb = (ck >> 2) * 32 + (ck & 3) * 4;
        bf16x8 o;
#pragma unroll
        for (int J = 0; J < 8; J++) o[J] = T[d][kb + (J & 3) + (J >> 2) * 16];
        *(bf16x8*)&dst[(size_t)d * Lc + t * 64 + ck * 8] = o;
    }
}

// ---------------- QKV GEMM: [8192][768] x [2304][768]^T, DMA-staged ---------------
// Writes compact Qc(scaled)/Kc/Vc via LDS-transposed coalesced stores.
__global__ __launch_bounds__(256, 2) void gemm_qkv_kernel(
    const __bf16* __restrict__ Ab, const __bf16* __restrict__ Bt,
    const float* __restrict__ bias,
    __bf16* __restrict__ Qc, __bf16* __restrict__ Kc, __bf16* __restrict__ Vc) {
    __shared__ __align__(16) char smem[34816];  // staging 32 KB; T tile 34 KB (reuse)
    __bf16* Al = (__bf16*)smem;                 // [128][64] swizzled
    __bf16* Bl = Al + 128 * 64;
    __bf16* T  = (__bf16*)smem;                 // [128][136] epilogue tile
    int tid = threadIdx.x;
    int wave = tid >> 6, lane = tid & 63;
    int quad = lane >> 4, l15 = lane & 15;
    int bm = blockIdx.x * 128, bn = blockIdx.y * 128;
    int wm = (wave >> 1) * 64, wn = (wave & 1) * 64;
    int swzA = tid & 7;
    f32x4 acc[4][4] = {};
    for (int k0 = 0; k0 < 768; k0 += 64) {
        __syncthreads();
#pragma unroll
        for (int j = 0; j < 4; j++) {
            int s = j * 256 + tid;
            int row = s >> 3;
            int ch = swzA ^ (row & 7);
            gl2lds16(&Ab[(size_t)(bm + row) * 768 + k0 + ch * 8],
                     (char*)smem + j * 4096 + wave * 1024);
            gl2lds16(&Bt[(size_t)(bn + row) * 768 + k0 + ch * 8],
                     (char*)smem + 16384 + j * 4096 + wave * 1024);
        }
        __syncthreads();
#pragma unroll
        for (int ks = 0; ks < 2; ks++) {
            bf16x8 af[4], bfr[4];
#pragma unroll
            for (int i = 0; i < 4; i++) {
                int row = wm + i * 16 + l15;
                af[i] = *(const bf16x8*)&Al[row * 64 + (((ks * 4 + quad) ^ (row & 7)) * 8)];
            }
#pragma unroll
            for (int j = 0; j < 4; j++) {
                int row = wn + j * 16 + l15;
                bfr[j] = *(const bf16x8*)&Bl[row * 64 + (((ks * 4 + quad) ^ (row & 7)) * 8)];
            }
#pragma unroll
            for (int i = 0; i < 4; i++)
#pragma unroll
                for (int j = 0; j < 4; j++)
                    acc[i][j] = MFMA_BF16(af[i], bfr[j], acc[i][j]);
        }
    }
    int which = blockIdx.y / 6;             // uniform: 0=Q 1=K 2=V
    int h0 = (blockIdx.y % 6) * 2;          // first head of this 128-col block
    float scl = which == 0 ? QSCALE : 1.0f;
    float bv[4];
#pragma unroll
    for (int j = 0; j < 4; j++) bv[j] = bias[bn + wn + j * 16 + l15];
    __syncthreads();  // done reading Al/Bl
#pragma unroll
    for (int i = 0; i < 4; i++)
#pragma unroll
        for (int j = 0; j < 4; j++) {
            int col = wn + j * 16 + l15;
#pragma unroll
            for (int r = 0; r < 4; r++) {
                int row = wm + i * 16 + quad * 4 + r;
                int ch = ((col >> 3) & 8) | (((col >> 3) & 7) ^ (row & 7));
                T[row * 136 + ch * 8 + (col & 7)] =
                    (__bf16)((acc[i][j][r] + bv[j]) * scl);
            }
        }
    __syncthreads();
    __bf16* dst = which == 0 ? Qc : (which == 1 ? Kc : Vc);
    int rr = tid >> 4;        // 0..15
    int c8 = tid & 15;        // 0..15
    int hh = c8 >> 3, d8 = c8 & 7;
    int h = h0 + hh;
    __bf16* p0 = dst + ((size_t)h * 2048 * 64) + d8 * 8;
    __bf16* p1 = dst + SEG1OFF + ((size_t)h * 4096 * 64) + d8 * 8;
    __bf16* p2 = dst + SEG2OFF + ((size_t)h * 2048 * 64) + d8 * 8;
#pragma unroll
    for (int pass = 0; pass < 8; pass++) {
        int row = pass * 16 + rr;
        int pos = bm + row;
        int ch = (c8 & 8) | ((c8 & 7) ^ (row & 7));
        bf16x8 v = *(const bf16x8*)&T[row * 136 + ch * 8];
        if (pos < 2048) *(bf16x8*)&p0[(size_t)pos * 64] = v;
        if (!(pos & 1)) *(bf16x8*)&p1[(size_t)(pos >> 1) * 64] = v;
        if (!(pos & 3)) *(bf16x8*)&p2[(size_t)(pos >> 2) * 64] = v;
    }
}

// ---------------- out-proj GEMM: 64x128 tiles for occupancy (768 blocks) ----------
__global__ __launch_bounds__(256) void gemm_out_kernel(
    const __bf16* __restrict__ Ab, const __bf16* __restrict__ Bt,
    const float* __restrict__ bias, float* __restrict__ Co) {
    __shared__ __align__(16) char smem[24576];
    __bf16* Al = (__bf16*)smem;           // [64][64] swizzled  (8 KB)
    __bf16* Bl = Al + 64 * 64;            // [128][64] swizzled (16 KB)
    int tid = threadIdx.x;
    int wave = tid >> 6, lane = tid & 63;
    int quad = lane >> 4, l15 = lane & 15;
    int bm = blockIdx.x * 64, bn = blockIdx.y * 128;
    int wn = wave * 32;
    f32x4 acc[4][2] = {};
    for (int k0 = 0; k0 < 768; k0 += 64) {
        __syncthreads();
#pragma unroll
        for (int j = 0; j < 2; j++) {
            int s = j * 256 + tid;
            int row = s >> 3;
            int ch = (s & 7) ^ (row & 7);
            gl2lds16(&Ab[(size_t)(bm + row) * 768 + k0 + ch * 8],
                     (char*)smem + j * 4096 + wave * 1024);
        }
#pragma unroll
        for (int j = 0; j < 4; j++) {
            int s = j * 256 + tid;
            int row = s >> 3;
            int ch = (s & 7) ^ (row & 7);
            gl2lds16(&Bt[(size_t)(bn + row) * 768 + k0 + ch * 8],
                     (char*)smem + 8192 + j * 4096 + wave * 1024);
        }
        __syncthreads();
#pragma unroll
        for (int ks = 0; ks < 2; ks++) {
            bf16x8 af[4], bfr[2];
#pragma unroll
            for (int i = 0; i < 4; i++) {
                int row = i * 16 + l15;
                af[i] = *(const bf16x8*)&Al[row * 64 + (((ks * 4 + quad) ^ (row & 7)) * 8)];
            }
#pragma unroll
            for (int j = 0; j < 2; j++) {
                int row = wn + j * 16 + l15;
                bfr[j] = *(const bf16x8*)&Bl[row * 64 + (((ks * 4 + quad) ^ (row & 7)) * 8)];
            }
#pragma unroll
            for (int i = 0; i < 4; i++)
#pragma unroll
                for (int j = 0; j < 2; j++)
                    acc[i][j] = MFMA_BF16(af[i], bfr[j], acc[i][j]);
        }
    }
#pragma unroll
    for (int j = 0; j < 2; j++) {
        int c = bn + wn + j * 16 + l15;
        float bv = bias[c];
#pragma unroll
        for (int i = 0; i < 4; i++)
#pragma unroll
            for (int r = 0; r < 4; r++) {
                int row = bm + i * 16 + quad * 4 + r;
                Co[(size_t)row * 768 + c] = acc[i][j][r] + bv;
            }
    }
}

// ---------------- fused flash attention: S^T, no-max, kv-split, dbuf DMA -----------
// 1920 blocks (seg0/seg2 32-iter first, seg1 in 4 kv-quarters of 16 iters).
// 32 q/wave (the r6-verified inner loop) + double-buffered K/V LDS: one barrier
// per iter; the DMA for iter nt+1 is issued right after the barrier publishing nt,
// so its vmcnt(0) drain (at barrier nt+2) has a full compute phase of slack.
// Safe: buf[(nt+1)&1] was last read in iter nt-1, and barrier nt proves all waves
// finished that read.
__global__ __launch_bounds__(256, 2) void attn_kernel(
    const __bf16* __restrict__ Qcb, const __bf16* __restrict__ Kcb,
    const __bf16* __restrict__ Vtb,
    float* __restrict__ O0, float* __restrict__ O1a, float* __restrict__ O1b,
    float* __restrict__ O1c, float* __restrict__ O1d, float* __restrict__ O2,
    float* __restrict__ L0, float* __restrict__ L1a, float* __restrict__ L1b,
    float* __restrict__ L1c, float* __restrict__ L1d, float* __restrict__ L2) {
    __shared__ __bf16 Kl[2 * 4096];
    __shared__ __bf16 Vl[2 * 4096];
    int bid = blockIdx.x;
    int seg, piece = 0, head, qt, Lc, iters;
    if (bid < 192)      { seg = 0; head = bid >> 4; qt = bid & 15; Lc = 2048; iters = 32; }
    else if (bid < 384) { int i = bid - 192; seg = 2; head = i >> 4; qt = i & 15; Lc = 2048; iters = 32; }
    else                { int i = bid - 384; seg = 1; head = i >> 7; int r = i & 127;
                          qt = r >> 2; piece = r & 3; Lc = 4096; iters = 16; }
    size_t soff = seg == 0 ? 0 : (seg == 1 ? SEG1OFF : SEG2OFF);
    const __bf16* Qh = Qcb + soff + (size_t)head * Lc * 64;
    const __bf16* Kh = Kcb + soff + (size_t)head * Lc * 64;
    const __bf16* Vh = Vtb + soff + (size_t)head * 64 * Lc;
    float* Ob;
    float* Lb;
    if (seg == 0)      { Ob = O0; Lb = L0 + head * 2048; }
    else if (seg == 2) { Ob = O2; Lb = L2 + head * 2048; }
    else {
        Ob = piece == 0 ? O1a : (piece == 1 ? O1b : (piece == 2 ? O1c : O1d));
        Lb = (piece == 0 ? L1a : (piece == 1 ? L1b : (piece == 2 ? L1c : L1d))) + head * 4096;
    }
    int kvb = piece * 16;
    int tid = threadIdx.x, wave = tid >> 6, lane = tid & 63;
    int quad = lane >> 4, l15 = lane & 15;
    bf16x8 qf[2][2];
#pragma unroll
    for (int qg = 0; qg < 2; qg++) {
        size_t qpos = (size_t)(qt * 128 + wave * 32 + qg * 16 + l15);
        qf[qg][0] = *(const bf16x8*)&Qh[qpos * 64 + quad * 8];
        qf[qg][1] = *(const bf16x8*)&Qh[qpos * 64 + 32 + quad * 8];
    }
    f32x4 o[2][4] = {};
    float lrun[2] = {0.f, 0.f};
    int kv0 = tid >> 3, cl0 = tid & 7;
    int kdb0 = cl0 ^ (kv0 & 7);
    int kv1 = kv0 + 32, kdb1 = cl0 ^ (kv1 & 7);
    char* KlB = (char*)Kl;
    char* VlB = (char*)Vl;
    int swz = l15 & 7;
    {   // prologue: buffer 0 <- tile kvb
        int t0 = kvb * 64;
        gl2lds16(&Kh[(size_t)(t0 + kv0) * 64 + kdb0 * 8], KlB + wave * 1024);
        gl2lds16(&Kh[(size_t)(t0 + kv1) * 64 + kdb1 * 8], KlB + 4096 + wave * 1024);
        gl2lds16(&Vh[(size_t)kv0 * Lc + t0 + kdb0 * 8], VlB + wave * 1024);
        gl2lds16(&Vh[(size_t)kv1 * Lc + t0 + kdb1 * 8], VlB + 4096 + wave * 1024);
    }
    for (int nt = 0; nt < iters; nt++) {
        __syncthreads();  // drains buf[nt&1]'s DMA; publishes it to all waves
        int cur = nt & 1;
        if (nt + 1 < iters) {
            int nb = 8192 * (cur ^ 1);
            int t1 = (kvb + nt + 1) * 64;
            gl2lds16(&Kh[(size_t)(t1 + kv0) * 64 + kdb0 * 8], KlB + nb + wave * 1024);
            gl2lds16(&Kh[(size_t)(t1 + kv1) * 64 + kdb1 * 8], KlB + nb + 4096 + wave * 1024);
            gl2lds16(&Vh[(size_t)kv0 * Lc + t1 + kdb0 * 8], VlB + nb + wave * 1024);
            gl2lds16(&Vh[(size_t)kv1 * Lc + t1 + kdb1 * 8], VlB + nb + 4096 + wave * 1024);
        }
        const __bf16* Kt = Kl + cur * 4096;
        const __bf16* Vt_ = Vl + cur * 4096;
        f32x4 sarr[4][2];
#pragma unroll
        for (int c = 0; c < 4; c++) {
            int krow = (c * 16 + l15) * 64;
            bf16x8 kf0 = *(const bf16x8*)&Kt[krow + ((quad ^ swz) * 8)];
            bf16x8 kf1 = *(const bf16x8*)&Kt[krow + (((4 + quad) ^ swz) * 8)];
#pragma unroll
            for (int qg = 0; qg < 2; qg++) {
                f32x4 z = {};
                z = MFMA_BF16(kf0, qf[qg][0], z);
                sarr[c][qg] = MFMA_BF16(kf1, qf[qg][1], z);
            }
        }
        union { bf16x8 v8; bf16x2 v2[4]; } pf8[2][2];
#pragma unroll
        for (int qg = 0; qg < 2; qg++)
#pragma unroll
            for (int c = 0; c < 4; c++) {
                float p0 = fexp2(sarr[c][qg][0]);
                float p1 = fexp2(sarr[c][qg][1]);
                float p2 = fexp2(sarr[c][qg][2]);
                float p3 = fexp2(sarr[c][qg][3]);
                lrun[qg] += (p0 + p1) + (p2 + p3);
                pf8[qg][c >> 1].v2[(c & 1) * 2 + 0] = pk_bf16(p0, p1);
                pf8[qg][c >> 1].v2[(c & 1) * 2 + 1] = pk_bf16(p2, p3);
            }
#pragma unroll
        for (int u = 0; u < 2; u++)
#pragma unroll
            for (int ds = 0; ds < 4; ds++) {
                int d = ds * 16 + l15;
                bf16x8 vf = *(const bf16x8*)&Vt_[d * 64 + (((u * 4 + quad) ^ swz) * 8)];
                o[0][ds] = MFMA_BF16(vf, pf8[0][u].v8, o[0][ds]);
                o[1][ds] = MFMA_BF16(vf, pf8[1][u].v8, o[1][ds]);
            }
    }
#pragma unroll
    for (int qg = 0; qg < 2; qg++) {
        float l = lrun[qg];
        l += __shfl_xor(l, 16, 64);
        l += __shfl_xor(l, 32, 64);
        int pos = qt * 128 + wave * 32 + qg * 16 + l15;
        float* orow = Ob + (size_t)pos * 768 + head * 64;
#pragma unroll
        for (int ds = 0; ds < 4; ds++)
            *(f32x4*)&orow[ds * 16 + quad * 4] = o[qg][ds];
        if (lane < 16) Lb[qt * 128 + wave * 32 + qg * 16 + lane] = l;
    }
}

// ---------------- combine: attnF[q][768] = (1/3) * sum_seg O_seg/l_seg, bf16 -------
__global__ __launch_bounds__(256) void combine_kernel(
    const float* __restrict__ O0, const float* __restrict__ O1a,
    const float* __restrict__ O1b, const float* __restrict__ O1c,
    const float* __restrict__ O1d, const float* __restrict__ O2,
    const float* __restrict__ L0, const float* __restrict__ L1a,
    const float* __restrict__ L1b, const float* __restrict__ L1c,
    const float* __restrict__ L1d, const float* __restrict__ L2,
    __bf16* __restrict__ attnF) {
    int g = blockIdx.x * 256 + threadIdx.x;  // 8192*96
    int q = g / 96;
    int cs = (g - q * 96) * 8;
    int head = cs >> 6;
    f32x4 a0 = {}, a1 = {};
    if (q < 2048) {
        float inv = 1.0f / L0[head * 2048 + q];
        const f32x4* p = (const f32x4*)&O0[(size_t)q * 768 + cs];
        a0 += p[0] * inv; a1 += p[1] * inv;
    }
    if (!(q & 1)) {
        int p1 = q >> 1;
        int li = head * 4096 + p1;
        float inv = 1.0f / (L1a[li] + L1b[li] + L1c[li] + L1d[li]);
        size_t ro = (size_t)p1 * 768 + cs;
        const f32x4* pa = (const f32x4*)&O1a[ro];
        const f32x4* pb = (const f32x4*)&O1b[ro];
        const f32x4* pc = (const f32x4*)&O1c[ro];
        const f32x4* pd = (const f32x4*)&O1d[ro];
        a0 += ((pa[0] + pb[0]) + (pc[0] + pd[0])) * inv;
        a1 += ((pa[1] + pb[1]) + (pc[1] + pd[1])) * inv;
    }
    if (!(q & 3)) {
        int p2 = q >> 2;
        float inv = 1.0f / L2[head * 2048 + p2];
        const f32x4* p = (const f32x4*)&O2[(size_t)p2 * 768 + cs];
        a0 += p[0] * inv; a1 += p[1] * inv;
    }
    const float third = 1.0f / 3.0f;
    bf16x8 ov;
    ov[0] = (__bf16)(a0[0] * third); ov[1] = (__bf16)(a0[1] * third);
    ov[2] = (__bf16)(a0[2] * third); ov[3] = (__bf16)(a0[3] * third);
    ov[4] = (__bf16)(a1[0] * third); ov[5] = (__bf16)(a1[1] * third);
    ov[6] = (__bf16)(a1[2] * third); ov[7] = (__bf16)(a1[3] * third);
    *(bf16x8*)&attnF[(size_t)q * 768 + cs] = ov;
}

extern "C" void kernel_launch(void* const* d_in, const int* in_sizes, int n_in,
                              void* d_out, int out_size, void* d_ws, size_t ws_size,
                              hipStream_t stream) {
    const float* x    = (const float*)d_in[0];
    const float* Wqkv = (const float*)d_in[1];
    const float* bqkv = (const float*)d_in[2];
    const float* Wout = (const float*)d_in[3];
    const float* bout = (const float*)d_in[4];
    float* out = (float*)d_out;
    (void)in_sizes; (void)n_in; (void)out_size; (void)ws_size;

    char* ws = (char*)d_ws;
    size_t off = 0;
    auto take = [&](size_t bytes) -> void* {
        void* p = ws + off;
        off += (bytes + 255) & ~(size_t)255;
        return p;
    };
    const size_t QKV_ELEMS = (size_t)12 * 8192 * 64;  // compact seg-major total
    __bf16* xb    = (__bf16*)take((size_t)8192 * 768 * 2);  // dead after gemm0 -> O0|O2
    __bf16* WqkvT = (__bf16*)take((size_t)2304 * 768 * 2);
    __bf16* WoutT = (__bf16*)take((size_t)768 * 768 * 2);
    __bf16* Qc    = (__bf16*)take(QKV_ELEMS * 2);           // attnF alias after attn
    __bf16* Kc    = (__bf16*)take(QKV_ELEMS * 2);
    __bf16* Vc    = (__bf16*)take(QKV_ELEMS * 2);           // dead after vtrans -> O1d
    __bf16* Vt    = (__bf16*)take(QKV_ELEMS * 2);
    float*  O1a   = (float*)take((size_t)4096 * 768 * 4);
    float*  O1b   = (float*)take((size_t)4096 * 768 * 4);
    float*  O1c   = (float*)take((size_t)4096 * 768 * 4);
    float*  L0    = (float*)take((size_t)12 * 2048 * 4);
    float*  L1a   = (float*)take((size_t)12 * 4096 * 4);
    float*  L1b   = (float*)take((size_t)12 * 4096 * 4);
    float*  L1c   = (float*)take((size_t)12 * 4096 * 4);
    float*  L1d   = (float*)take((size_t)12 * 4096 * 4);
    float*  L2    = (float*)take((size_t)12 * 2048 * 4);
    float*  O0    = (float*)xb;                 // 2048*768 f32 = 6.29 MB
    float*  O2    = O0 + (size_t)2048 * 768;    // next 6.29 MB (xb is 12.58 MB)
    float*  O1d   = (float*)Vc;                 // 4096*768 f32 = 12.58 MB = |Vc|
    __bf16* attnF = Qc;                         // Qc dead after attn_kernel

    prep_kernel<<<4224, 256, 0, stream>>>(x, Wqkv, Wout, xb, WqkvT, WoutT);
    gemm_qkv_kernel<<<dim3(64, 18), 256, 0, stream>>>(xb, WqkvT, bqkv, Qc, Kc, Vc);
    vtrans_kernel<<<1536, 256, 0, stream>>>(Vc, Vt);
    attn_kernel<<<1920, 256, 0, stream>>>(Qc, Kc, Vt, O0, O1a, O1b, O1c, O1d, O2,
                                          L0, L1a, L1b, L1c, L1d, L2);
    combine_kernel<<<3072, 256, 0, stream>>>(O0, O1a, O1b, O1c, O1d, O2,
                                             L0, L1a, L1b, L1c, L1d, L2, attnF);
    gemm_out_kernel<<<dim3(128, 6), 256, 0, stream>>>(attnF, WoutT, bout, out);
}

// Round 9
// 239.543 us; speedup vs baseline: 1.3828x; 1.0173x over previous
//
#include <hip/hip_runtime.h>
#include <hip/hip_bf16.h>

typedef float f32x4 __attribute__((ext_vector_type(4)));
typedef float fvec4 __attribute__((ext_vector_type(4)));
typedef __bf16 bf16x8 __attribute__((ext_vector_type(8)));
typedef __bf16 bf16x2 __attribute__((ext_vector_type(2)));

__device__ inline float fexp2(float x) {
#if __has_builtin(__builtin_amdgcn_exp2f)
    return __builtin_amdgcn_exp2f(x);
#else
    return exp2f(x);
#endif
}

// packed f32x2 -> bf16x2 (single v_cvt_pk_bf16_f32 when available)
__device__ __forceinline__ bf16x2 pk_bf16(float a, float b) {
#if __has_builtin(__builtin_amdgcn_cvt_pk_bf16_f32)
    auto t = __builtin_amdgcn_cvt_pk_bf16_f32(a, b);
    return __builtin_bit_cast(bf16x2, t);
#else
    bf16x2 r; r[0] = (__bf16)a; r[1] = (__bf16)b; return r;
#endif
}

#define MFMA_BF16(a, b, c) __builtin_amdgcn_mfma_f32_16x16x32_bf16((a), (b), (c), 0, 0, 0)

__device__ __forceinline__ void gl2lds16(const void* g, void* l) {
    __builtin_amdgcn_global_load_lds((const __attribute__((address_space(1))) void*)g,
                                     (__attribute__((address_space(3))) void*)l, 16, 0, 0);
}

// seg offsets (elements) inside compact Q/K/V buffers: [seg0 12x2048][seg1 12x4096][seg2 12x2048] x64d
#define SEG1OFF ((size_t)12 * 2048 * 64)
#define SEG2OFF ((size_t)12 * 6144 * 64)
#define QSCALE 0.18033688f  // SCALE * log2(e)

// ---------------- fused prep: x->bf16 cvt + both weight transposes ----------------
__global__ __launch_bounds__(256) void prep_kernel(
    const float* __restrict__ x, const float* __restrict__ Wqkv,
    const float* __restrict__ Wout, __bf16* __restrict__ xb,
    __bf16* __restrict__ WqkvT, __bf16* __restrict__ WoutT) {
    int bid = blockIdx.x, tid = threadIdx.x;
    if (bid < 3072) {
        int i = bid * 256 + tid;
        fvec4 a = ((const fvec4*)x)[2 * i];
        fvec4 b = ((const fvec4*)x)[2 * i + 1];
        bf16x8 o;
        o[0] = (__bf16)a[0]; o[1] = (__bf16)a[1]; o[2] = (__bf16)a[2]; o[3] = (__bf16)a[3];
        o[4] = (__bf16)b[0]; o[5] = (__bf16)b[1]; o[6] = (__bf16)b[2]; o[7] = (__bf16)b[3];
        ((bf16x8*)xb)[i] = o;
    } else if (bid < 3936) {
        int b = bid - 3072;
        int n = (b % 9) * 256 + tid;  // 0..2303
        int kg = b / 9;               // 0..95
        bf16x8 o;
#pragma unroll
        for (int j = 0; j < 8; j++) o[j] = (__bf16)Wqkv[(size_t)(kg * 8 + j) * 2304 + n];
        *(bf16x8*)&WqkvT[(size_t)n * 768 + kg * 8] = o;
    } else {
        int b = bid - 3936;
        int n = (b % 3) * 256 + tid;  // 0..767
        int kg = b / 3;               // 0..95
        bf16x8 o;
#pragma unroll
        for (int j = 0; j < 8; j++) o[j] = (__bf16)Wout[(size_t)(kg * 8 + j) * 768 + n];
        *(bf16x8*)&WoutT[(size_t)n * 768 + kg * 8] = o;
    }
}

// ---- Vc compact [seg][head][pos][64] -> Vt [seg][head][64][Lc] in MFMA-k order ----
__global__ __launch_bounds__(256) void vtrans_kernel(const __bf16* __restrict__ Vc,
                                                     __bf16* __restrict__ Vt) {
    __shared__ __bf16 T[64][68];
    int bid = blockIdx.x;
    int Lc, head, t;
    size_t soff;
    if (bid < 768)       { Lc = 4096; head = bid >> 6; t = bid & 63; soff = SEG1OFF; }
    else if (bid < 1152) { int i = bid - 768; Lc = 2048; head = i >> 5; t = i & 31; soff = 0; }
    else                 { int i = bid - 1152; Lc = 2048; head = i >> 5; t = i & 31; soff = SEG2OFF; }
    const __bf16* src = Vc + soff + (size_t)head * Lc * 64;
    __bf16* dst = Vt + soff + (size_t)head * 64 * Lc;
    int tid = threadIdx.x;
#pragma unroll
    for (int it = 0; it < 2; it++) {
        int s = tid + it * 256;
        int kvr = s >> 3, d8 = (s & 7) * 8;
        bf16x8 vv = *(const bf16x8*)&src[(size_t)(t * 64 + kvr) * 64 + d8];
#pragma unroll
        for (int j = 0; j < 8; j++) T[d8 + j][kvr] = vv[j];
    }
    __syncthreads();
#pragma unroll
    for (int it = 0; it < 2; it++) {
        int s = tid + it * 256;
        int d = s >> 3, ck = s & 7;
        int kb = (ck >> 2) * 32 + (ck & 3) * 4;
        bf16x8 o;
#pragma unroll
        for (int J = 0; J < 8; J++) o[J] = T[d][kb + (J & 3) + (J >> 2) * 16];
        *(bf16x8*)&dst[(size_t)d * Lc + t * 64 + ck * 8] = o;
    }
}

// ---------------- QKV GEMM: [8192][768] x [2304][768]^T, dbuf DMA-staged ----------
// Double-buffered staging (64 KB): DMA for k-iter ki+1 issued right after the
// barrier publishing ki, so its vmcnt(0) drain has a full compute phase of slack.
// Epilogue T-tile (34.8 KB) overlays the dead staging buffers.
__global__ __launch_bounds__(256, 2) void gemm_qkv_kernel(
    const __bf16* __restrict__ Ab, const __bf16* __restrict__ Bt,
    const float* __restrict__ bias,
    __bf16* __restrict__ Qc, __bf16* __restrict__ Kc, __bf16* __restrict__ Vc) {
    __shared__ __align__(16) char smem[65536];  // 2 x (A 16K + B 16K); T tile reuse
    __bf16* T = (__bf16*)smem;                  // [128][136] epilogue tile
    int tid = threadIdx.x;
    int wave = tid >> 6, lane = tid & 63;
    int quad = lane >> 4, l15 = lane & 15;
    int bm = blockIdx.x * 128, bn = blockIdx.y * 128;
    int wm = (wave >> 1) * 64, wn = (wave & 1) * 64;
    int swzA = tid & 7;
    // DMA slot decode (per j: slot s = j*256+tid -> row s>>3, chunk (s&7)^(row&7))
    int rows_[4], chs_[4];
#pragma unroll
    for (int j = 0; j < 4; j++) {
        int s = j * 256 + tid;
        rows_[j] = s >> 3;
        chs_[j] = swzA ^ (rows_[j] & 7);
    }
    f32x4 acc[4][4] = {};
    {   // prologue: buf0 <- k0=0
#pragma unroll
        for (int j = 0; j < 4; j++) {
            gl2lds16(&Ab[(size_t)(bm + rows_[j]) * 768 + chs_[j] * 8],
                     smem + j * 4096 + wave * 1024);
            gl2lds16(&Bt[(size_t)(bn + rows_[j]) * 768 + chs_[j] * 8],
                     smem + 16384 + j * 4096 + wave * 1024);
        }
    }
    for (int ki = 0; ki < 12; ki++) {
        __syncthreads();  // drains buf[ki&1]'s DMA; publishes to all waves
        int cur = ki & 1;
        if (ki + 1 < 12) {
            int nb = (cur ^ 1) * 32768;
            int k1 = (ki + 1) * 64;
#pragma unroll
            for (int j = 0; j < 4; j++) {
                gl2lds16(&Ab[(size_t)(bm + rows_[j]) * 768 + k1 + chs_[j] * 8],
                         smem + nb + j * 4096 + wave * 1024);
                gl2lds16(&Bt[(size_t)(bn + rows_[j]) * 768 + k1 + chs_[j] * 8],
                         smem + nb + 16384 + j * 4096 + wave * 1024);
            }
        }
        const __bf16* Al = (const __bf16*)(smem + cur * 32768);
        const __bf16* Bl = Al + 8192;
#pragma unroll
        for (int ks = 0; ks < 2; ks++) {
            bf16x8 af[4], bfr[4];
#pragma unroll
            for (int i = 0; i < 4; i++) {
                int row = wm + i * 16 + l15;
                af[i] = *(const bf16x8*)&Al[row * 64 + (((ks * 4 + quad) ^ (row & 7)) * 8)];
            }
#pragma unroll
            for (int j = 0; j < 4; j++) {
                int row = wn + j * 16 + l15;
                bfr[j] = *(const bf16x8*)&Bl[row * 64 + (((ks * 4 + quad) ^ (row & 7)) * 8)];
            }
#pragma unroll
            for (int i = 0; i < 4; i++)
#pragma unroll
                for (int j = 0; j < 4; j++)
                    acc[i][j] = MFMA_BF16(af[i], bfr[j], acc[i][j]);
        }
    }
    int which = blockIdx.y / 6;             // uniform: 0=Q 1=K 2=V
    int h0 = (blockIdx.y % 6) * 2;          // first head of this 128-col block
    float scl = which == 0 ? QSCALE : 1.0f;
    float bv[4];
#pragma unroll
    for (int j = 0; j < 4; j++) bv[j] = bias[bn + wn + j * 16 + l15];
    __syncthreads();  // done reading staging; T overlays it
#pragma unroll
    for (int i = 0; i < 4; i++)
#pragma unroll
        for (int j = 0; j < 4; j++) {
            int col = wn + j * 16 + l15;
#pragma unroll
            for (int r = 0; r < 4; r++) {
                int row = wm + i * 16 + quad * 4 + r;
                int ch = ((col >> 3) & 8) | (((col >> 3) & 7) ^ (row & 7));
                T[row * 136 + ch * 8 + (col & 7)] =
                    (__bf16)((acc[i][j][r] + bv[j]) * scl);
            }
        }
    __syncthreads();
    __bf16* dst = which == 0 ? Qc : (which == 1 ? Kc : Vc);
    int rr = tid >> 4;        // 0..15
    int c8 = tid & 15;        // 0..15
    int hh = c8 >> 3, d8 = c8 & 7;
    int h = h0 + hh;
    __bf16* p0 = dst + ((size_t)h * 2048 * 64) + d8 * 8;
    __bf16* p1 = dst + SEG1OFF + ((size_t)h * 4096 * 64) + d8 * 8;
    __bf16* p2 = dst + SEG2OFF + ((size_t)h * 2048 * 64) + d8 * 8;
#pragma unroll
    for (int pass = 0; pass < 8; pass++) {
        int row = pass * 16 + rr;
        int pos = bm + row;
        int ch = (c8 & 8) | ((c8 & 7) ^ (row & 7));
        bf16x8 v = *(const bf16x8*)&T[row * 136 + ch * 8];
        if (pos < 2048) *(bf16x8*)&p0[(size_t)pos * 64] = v;
        if (!(pos & 1)) *(bf16x8*)&p1[(size_t)(pos >> 1) * 64] = v;
        if (!(pos & 3)) *(bf16x8*)&p2[(size_t)(pos >> 2) * 64] = v;
    }
}

// ---------------- out-proj GEMM: 64x128 tiles, dbuf DMA-staged (768 blocks) -------
__global__ __launch_bounds__(256) void gemm_out_kernel(
    const __bf16* __restrict__ Ab, const __bf16* __restrict__ Bt,
    const float* __restrict__ bias, float* __restrict__ Co) {
    __shared__ __align__(16) char smem[49152];  // 2 x (A 8K + B 16K)
    int tid = threadIdx.x;
    int wave = tid >> 6, lane = tid & 63;
    int quad = lane >> 4, l15 = lane & 15;
    int bm = blockIdx.x * 64, bn = blockIdx.y * 128;
    int wn = wave * 32;
    int rowsA[2], chsA[2], rowsB[4], chsB[4];
#pragma unroll
    for (int j = 0; j < 2; j++) {
        int s = j * 256 + tid;
        rowsA[j] = s >> 3;
        chsA[j] = (s & 7) ^ (rowsA[j] & 7);
    }
#pragma unroll
    for (int j = 0; j < 4; j++) {
        int s = j * 256 + tid;
        rowsB[j] = s >> 3;
        chsB[j] = (s & 7) ^ (rowsB[j] & 7);
    }
    f32x4 acc[4][2] = {};
    {   // prologue: buf0 <- k0=0
#pragma unroll
        for (int j = 0; j < 2; j++)
            gl2lds16(&Ab[(size_t)(bm + rowsA[j]) * 768 + chsA[j] * 8],
                     smem + j * 4096 + wave * 1024);
#pragma unroll
        for (int j = 0; j < 4; j++)
            gl2lds16(&Bt[(size_t)(bn + rowsB[j]) * 768 + chsB[j] * 8],
                     smem + 8192 + j * 4096 + wave * 1024);
    }
    for (int ki = 0; ki < 12; ki++) {
        __syncthreads();
        int cur = ki & 1;
        if (ki + 1 < 12) {
            int nb = (cur ^ 1) * 24576;
            int k1 = (ki + 1) * 64;
#pragma unroll
            for (int j = 0; j < 2; j++)
                gl2lds16(&Ab[(size_t)(bm + rowsA[j]) * 768 + k1 + chsA[j] * 8],
                         smem + nb + j * 4096 + wave * 1024);
#pragma unroll
            for (int j = 0; j < 4; j++)
                gl2lds16(&Bt[(size_t)(bn + rowsB[j]) * 768 + k1 + chsB[j] * 8],
                         smem + nb + 8192 + j * 4096 + wave * 1024);
        }
        const __bf16* Al = (const __bf16*)(smem + cur * 24576);
        const __bf16* Bl = Al + 4096;
#pragma unroll
        for (int ks = 0; ks < 2; ks++) {
            bf16x8 af[4], bfr[2];
#pragma unroll
            for (int i = 0; i < 4; i++) {
                int row = i * 16 + l15;
                af[i] = *(const bf16x8*)&Al[row * 64 + (((ks * 4 + quad) ^ (row & 7)) * 8)];
            }
#pragma unroll
            for (int j = 0; j < 2; j++) {
                int row = wn + j * 16 + l15;
                bfr[j] = *(const bf16x8*)&Bl[row * 64 + (((ks * 4 + quad) ^ (row & 7)) * 8)];
            }
#pragma unroll
            for (int i = 0; i < 4; i++)
#pragma unroll
                for (int j = 0; j < 2; j++)
                    acc[i][j] = MFMA_BF16(af[i], bfr[j], acc[i][j]);
        }
    }
#pragma unroll
    for (int j = 0; j < 2; j++) {
        int c = bn + wn + j * 16 + l15;
        float bv = bias[c];
#pragma unroll
        for (int i = 0; i < 4; i++)
#pragma unroll
            for (int r = 0; r < 4; r++) {
                int row = bm + i * 16 + quad * 4 + r;
                Co[(size_t)row * 768 + c] = acc[i][j][r] + bv;
            }
    }
}

// ---------------- fused flash attention: S^T, no-max, kv-split, dbuf DMA -----------
// 1920 blocks (seg0/seg2 32-iter first, seg1 in 4 kv-quarters of 16 iters).
// Softmax denominator via MFMA(ones, P): full kv row-sums land in C-layout (all
// lanes of a column identical) -> no VALU adds in the loop, no epilogue shuffles.
__global__ __launch_bounds__(256, 2) void attn_kernel(
    const __bf16* __restrict__ Qcb, const __bf16* __restrict__ Kcb,
    const __bf16* __restrict__ Vtb,
    float* __restrict__ O0, float* __restrict__ O1a, float* __restrict__ O1b,
    float* __restrict__ O1c, float* __restrict__ O1d, float* __restrict__ O2,
    float* __restrict__ L0, float* __restrict__ L1a, float* __restrict__ L1b,
    float* __restrict__ L1c, float* __restrict__ L1d, float* __restrict__ L2) {
    __shared__ __bf16 Kl[2 * 4096];
    __shared__ __bf16 Vl[2 * 4096];
    int bid = blockIdx.x;
    int seg, piece = 0, head, qt, Lc, iters;
    if (bid < 192)      { seg = 0; head = bid >> 4; qt = bid & 15; Lc = 2048; iters = 32; }
    else if (bid < 384) { int i = bid - 192; seg = 2; head = i >> 4; qt = i & 15; Lc = 2048; iters = 32; }
    else                { int i = bid - 384; seg = 1; head = i >> 7; int r = i & 127;
                          qt = r >> 2; piece = r & 3; Lc = 4096; iters = 16; }
    size_t soff = seg == 0 ? 0 : (seg == 1 ? SEG1OFF : SEG2OFF);
    const __bf16* Qh = Qcb + soff + (size_t)head * Lc * 64;
    const __bf16* Kh = Kcb + soff + (size_t)head * Lc * 64;
    const __bf16* Vh = Vtb + soff + (size_t)head * 64 * Lc;
    float* Ob;
    float* Lb;
    if (seg == 0)      { Ob = O0; Lb = L0 + head * 2048; }
    else if (seg == 2) { Ob = O2; Lb = L2 + head * 2048; }
    else {
        Ob = piece == 0 ? O1a : (piece == 1 ? O1b : (piece == 2 ? O1c : O1d));
        Lb = (piece == 0 ? L1a : (piece == 1 ? L1b : (piece == 2 ? L1c : L1d))) + head * 4096;
    }
    int kvb = piece * 16;
    int tid = threadIdx.x, wave = tid >> 6, lane = tid & 63;
    int quad = lane >> 4, l15 = lane & 15;
    bf16x8 qf[2][2];
#pragma unroll
    for (int qg = 0; qg < 2; qg++) {
        size_t qpos = (size_t)(qt * 128 + wave * 32 + qg * 16 + l15);
        qf[qg][0] = *(const bf16x8*)&Qh[qpos * 64 + quad * 8];
        qf[qg][1] = *(const bf16x8*)&Qh[qpos * 64 + 32 + quad * 8];
    }
    f32x4 o[2][4] = {};
    f32x4 lacc[2] = {};
    bf16x8 ones;
#pragma unroll
    for (int j = 0; j < 8; j++) ones[j] = (__bf16)1.0f;
    int kv0 = tid >> 3, cl0 = tid & 7;
    int kdb0 = cl0 ^ (kv0 & 7);
    int kv1 = kv0 + 32, kdb1 = cl0 ^ (kv1 & 7);
    char* KlB = (char*)Kl;
    char* VlB = (char*)Vl;
    int swz = l15 & 7;
    {   // prologue: buffer 0 <- tile kvb
        int t0 = kvb * 64;
        gl2lds16(&Kh[(size_t)(t0 + kv0) * 64 + kdb0 * 8], KlB + wave * 1024);
        gl2lds16(&Kh[(size_t)(t0 + kv1) * 64 + kdb1 * 8], KlB + 4096 + wave * 1024);
        gl2lds16(&Vh[(size_t)kv0 * Lc + t0 + kdb0 * 8], VlB + wave * 1024);
        gl2lds16(&Vh[(size_t)kv1 * Lc + t0 + kdb1 * 8], VlB + 4096 + wave * 1024);
    }
    for (int nt = 0; nt < iters; nt++) {
        __syncthreads();  // drains buf[nt&1]'s DMA; publishes it to all waves
        int cur = nt & 1;
        if (nt + 1 < iters) {
            int nb = 8192 * (cur ^ 1);
            int t1 = (kvb + nt + 1) * 64;
            gl2lds16(&Kh[(size_t)(t1 + kv0) * 64 + kdb0 * 8], KlB + nb + wave * 1024);
            gl2lds16(&Kh[(size_t)(t1 + kv1) * 64 + kdb1 * 8], KlB + nb + 4096 + wave * 1024);
            gl2lds16(&Vh[(size_t)kv0 * Lc + t1 + kdb0 * 8], VlB + nb + wave * 1024);
            gl2lds16(&Vh[(size_t)kv1 * Lc + t1 + kdb1 * 8], VlB + nb + 4096 + wave * 1024);
        }
        const __bf16* Kt = Kl + cur * 4096;
        const __bf16* Vt_ = Vl + cur * 4096;
        f32x4 sarr[4][2];
#pragma unroll
        for (int c = 0; c < 4; c++) {
            int krow = (c * 16 + l15) * 64;
            bf16x8 kf0 = *(const bf16x8*)&Kt[krow + ((quad ^ swz) * 8)];
            bf16x8 kf1 = *(const bf16x8*)&Kt[krow + (((4 + quad) ^ swz) * 8)];
#pragma unroll
            for (int qg = 0; qg < 2; qg++) {
                f32x4 z = {};
                z = MFMA_BF16(kf0, qf[qg][0], z);
                sarr[c][qg] = MFMA_BF16(kf1, qf[qg][1], z);
            }
        }
        union { bf16x8 v8; bf16x2 v2[4]; } pf8[2][2];
#pragma unroll
        for (int qg = 0; qg < 2; qg++)
#pragma unroll
            for (int c = 0; c < 4; c++) {
                float p0 = fexp2(sarr[c][qg][0]);
                float p1 = fexp2(sarr[c][qg][1]);
                float p2 = fexp2(sarr[c][qg][2]);
                float p3 = fexp2(sarr[c][qg][3]);
                pf8[qg][c >> 1].v2[(c & 1) * 2 + 0] = pk_bf16(p0, p1);
                pf8[qg][c >> 1].v2[(c & 1) * 2 + 1] = pk_bf16(p2, p3);
            }
#pragma unroll
        for (int u = 0; u < 2; u++) {
#pragma unroll
            for (int ds = 0; ds < 4; ds++) {
                int d = ds * 16 + l15;
                bf16x8 vf = *(const bf16x8*)&Vt_[d * 64 + (((u * 4 + quad) ^ swz) * 8)];
                o[0][ds] = MFMA_BF16(vf, pf8[0][u].v8, o[0][ds]);
                o[1][ds] = MFMA_BF16(vf, pf8[1][u].v8, o[1][ds]);
            }
            lacc[0] = MFMA_BF16(ones, pf8[0][u].v8, lacc[0]);
            lacc[1] = MFMA_BF16(ones, pf8[1][u].v8, lacc[1]);
        }
    }
#pragma unroll
    for (int qg = 0; qg < 2; qg++) {
        float l = lacc[qg][0];  // rows redundant: every lane has its column's sum
        int pos = qt * 128 + wave * 32 + qg * 16 + l15;
        float* orow = Ob + (size_t)pos * 768 + head * 64;
#pragma unroll
        for (int ds = 0; ds < 4; ds++)
            *(f32x4*)&orow[ds * 16 + quad * 4] = o[qg][ds];
        if (lane < 16) Lb[qt * 128 + wave * 32 + qg * 16 + lane] = l;
    }
}

// ---------------- combine: attnF[q][768] = (1/3) * sum_seg O_seg/l_seg, bf16 -------
__global__ __launch_bounds__(256) void combine_kernel(
    const float* __restrict__ O0, const float* __restrict__ O1a,
    const float* __restrict__ O1b, const float* __restrict__ O1c,
    const float* __restrict__ O1d, const float* __restrict__ O2,
    const float* __restrict__ L0, const float* __restrict__ L1a,
    const float* __restrict__ L1b, const float* __restrict__ L1c,
    const float* __restrict__ L1d, const float* __restrict__ L2,
    __bf16* __restrict__ attnF) {
    int g = blockIdx.x * 256 + threadIdx.x;  // 8192*96
    int q = g / 96;
    int cs = (g - q * 96) * 8;
    int head = cs >> 6;
    f32x4 a0 = {}, a1 = {};
    if (q < 2048) {
        float inv = 1.0f / L0[head * 2048 + q];
        const f32x4* p = (const f32x4*)&O0[(size_t)q * 768 + cs];
        a0 += p[0] * inv; a1 += p[1] * inv;
    }
    if (!(q & 1)) {
        int p1 = q >> 1;
        int li = head * 4096 + p1;
        float inv = 1.0f / (L1a[li] + L1b[li] + L1c[li] + L1d[li]);
        size_t ro = (size_t)p1 * 768 + cs;
        const f32x4* pa = (const f32x4*)&O1a[ro];
        const f32x4* pb = (const f32x4*)&O1b[ro];
        const f32x4* pc = (const f32x4*)&O1c[ro];
        const f32x4* pd = (const f32x4*)&O1d[ro];
        a0 += ((pa[0] + pb[0]) + (pc[0] + pd[0])) * inv;
        a1 += ((pa[1] + pb[1]) + (pc[1] + pd[1])) * inv;
    }
    if (!(q & 3)) {
        int p2 = q >> 2;
        float inv = 1.0f / L2[head * 2048 + p2];
        const f32x4* p = (const f32x4*)&O2[(size_t)p2 * 768 + cs];
        a0 += p[0] * inv; a1 += p[1] * inv;
    }
    const float third = 1.0f / 3.0f;
    bf16x8 ov;
    ov[0] = (__bf16)(a0[0] * third); ov[1] = (__bf16)(a0[1] * third);
    ov[2] = (__bf16)(a0[2] * third); ov[3] = (__bf16)(a0[3] * third);
    ov[4] = (__bf16)(a1[0] * third); ov[5] = (__bf16)(a1[1] * third);
    ov[6] = (__bf16)(a1[2] * third); ov[7] = (__bf16)(a1[3] * third);
    *(bf16x8*)&attnF[(size_t)q * 768 + cs] = ov;
}

extern "C" void kernel_launch(void* const* d_in, const int* in_sizes, int n_in,
                              void* d_out, int out_size, void* d_ws, size_t ws_size,
                              hipStream_t stream) {
    const float* x    = (const float*)d_in[0];
    const float* Wqkv = (const float*)d_in[1];
    const float* bqkv = (const float*)d_in[2];
    const float* Wout = (const float*)d_in[3];
    const float* bout = (const float*)d_in[4];
    float* out = (float*)d_out;
    (void)in_sizes; (void)n_in; (void)out_size; (void)ws_size;

    char* ws = (char*)d_ws;
    size_t off = 0;
    auto take = [&](size_t bytes) -> void* {
        void* p = ws + off;
        off += (bytes + 255) & ~(size_t)255;
        return p;
    };
    const size_t QKV_ELEMS = (size_t)12 * 8192 * 64;  // compact seg-major total
    __bf16* xb    = (__bf16*)take((size_t)8192 * 768 * 2);  // dead after gemm0 -> O0|O2
    __bf16* WqkvT = (__bf16*)take((size_t)2304 * 768 * 2);
    __bf16* WoutT = (__bf16*)take((size_t)768 * 768 * 2);
    __bf16* Qc    = (__bf16*)take(QKV_ELEMS * 2);           // attnF alias after attn
    __bf16* Kc    = (__bf16*)take(QKV_ELEMS * 2);
    __bf16* Vc    = (__bf16*)take(QKV_ELEMS * 2);           // dead after vtrans -> O1d
    __bf16* Vt    = (__bf16*)take(QKV_ELEMS * 2);
    float*  O1a   = (float*)take((size_t)4096 * 768 * 4);
    float*  O1b   = (float*)take((size_t)4096 * 768 * 4);
    float*  O1c   = (float*)take((size_t)4096 * 768 * 4);
    float*  L0    = (float*)take((size_t)12 * 2048 * 4);
    float*  L1a   = (float*)take((size_t)12 * 4096 * 4);
    float*  L1b   = (float*)take((size_t)12 * 4096 * 4);
    float*  L1c   = (float*)take((size_t)12 * 4096 * 4);
    float*  L1d   = (float*)take((size_t)12 * 4096 * 4);
    float*  L2    = (float*)take((size_t)12 * 2048 * 4);
    float*  O0    = (float*)xb;                 // 2048*768 f32 = 6.29 MB
    float*  O2    = O0 + (size_t)2048 * 768;    // next 6.29 MB (xb is 12.58 MB)
    float*  O1d   = (float*)Vc;                 // 4096*768 f32 = 12.58 MB = |Vc|
    __bf16* attnF = Qc;                         // Qc dead after attn_kernel

    prep_kernel<<<4224, 256, 0, stream>>>(x, Wqkv, Wout, xb, WqkvT, WoutT);
    gemm_qkv_kernel<<<dim3(64, 18), 256, 0, stream>>>(xb, WqkvT, bqkv, Qc, Kc, Vc);
    vtrans_kernel<<<1536, 256, 0, stream>>>(Vc, Vt);
    attn_kernel<<<1920, 256, 0, stream>>>(Qc, Kc, Vt, O0, O1a, O1b, O1c, O1d, O2,
                                          L0, L1a, L1b, L1c, L1d, L2);
    combine_kernel<<<3072, 256, 0, stream>>>(O0, O1a, O1b, O1c, O1d, O2,
                                             L0, L1a, L1b, L1c, L1d, L2, attnF);
    gemm_out_kernel<<<dim3(128, 6), 256, 0, stream>>>(attnF, WoutT, bout, out);
}